// Round 20
// baseline (210.292 us; speedup 1.0000x reference)
//
#include <hip/hip_runtime.h>
#include <hip/hip_bf16.h>

// Sizes (fixed by the reference setup)
constexpr int B  = 128;
constexpr int D  = 1024;
constexpr int NV = 36;
constexpr int NL = 20;
constexpr int BD = B * D;              // 131072
constexpr float EPS = 0.01f;
constexpr int NSLOT = 10;

// bf16 partial-slot offsets (in SHORT elements from ws base)
constexpr long SLs  = 524288;                 // [128][4096] bf16 slot
constexpr long SLBs = 2097152;                // [512][4096] bf16 slot
constexpr long SLCs = 524288;                 // [512][1024] bf16 slot
constexpr long SGPA  = 0;                     // 8 att-gate slots
constexpr long SGPLB = SGPA + 8 * SLs;        // 4 lbase slots
constexpr long SGPB  = SGPLB + 4 * SLs;       // 4 lang-gate slots
constexpr long SGPC  = SGPB + 4 * SLBs;       // 4 conf slots

// float offsets (from ws base, after the partial region)
constexpr long FBASE     = (SGPC + 4 * SLCs) / 2;   // floats
constexpr long OFF_HATT  = FBASE;                   // h_att f32 [128][1024]
constexpr long OFF_HLB   = OFF_HATT + BD;           // hB [512][1024]
constexpr long OFF_CLB   = OFF_HLB + 524288;        // cB
constexpr long OFF_VVB   = OFF_CLB + 524288;        // bf16 vval cache
constexpr long OFF_LVB   = OFF_VVB + 2359296;
constexpr long OFF_VKB   = OFF_LVB + 1310720;
constexpr long OFF_LKB   = OFF_VKB + 2359296;
constexpr long OFF_HATB  = OFF_LKB + 1310720;       // bf16 h_att
constexpr long OFF_VCXB  = OFF_HATB + 65536;        // bf16 vctx [512][1024]
constexpr long OFF_LCXB  = OFF_VCXB + 262144;       // bf16 lctx

typedef float f32x4 __attribute__((ext_vector_type(4)));
typedef short s16x8 __attribute__((ext_vector_type(8)));
typedef short ldsT[128][72];

__device__ __forceinline__ float sigf(float x) { return 1.f / (1.f + expf(-x)); }

__device__ __forceinline__ short f2bf(float f) {
  __hip_bfloat16 h = __float2bfloat16(f);
  return *reinterpret_cast<short*>(&h);
}
__device__ __forceinline__ float bf2f(short s) {
  unsigned u = ((unsigned)(unsigned short)s) << 16;
  return __uint_as_float(u);
}
__device__ __forceinline__ f32x4 LD4(const float* p) { return *(const f32x4*)p; }
__device__ __forceinline__ void ST4(float* p, f32x4 v) { *(f32x4*)p = v; }
__device__ __forceinline__ f32x4 ld4bf(const short* p) {
  short4 s = *(const short4*)p;
  return (f32x4){bf2f(s.x), bf2f(s.y), bf2f(s.z), bf2f(s.w)};
}

// d_out section offsets
constexpr long O1 = BD;
constexpr long O2 = O1 + (long)B * NV * D;
constexpr long O3 = O2 + (long)B * NL * D;
constexpr long O4 = O3 + B;
constexpr long O5 = O4 + 2L * BD;
constexpr long O6 = O5 + 2L * BD;
constexpr long O7 = O6 + BD;
constexpr long VK = (long)B * NV * D;
constexpr long LK = (long)B * NL * D;

// ---------------------------------------------------------------------------
// GEMM body: tile BM=128 BN=128 BK=64, 512 threads = 8 waves (2x4), acc[4][2].
// Single-buffered LDS (36 KB) + 2-DEEP register prefetch (ping-pong A/B reg
// sets): G(t+2) issued at end of tile t, consumed end of tile t+1 -> HBM
// latency covered by a FULL tile (~1000 cyc), not just the MFMA phase.
// Writes bf16 partials. A may be f32 or bf16. Per-slot klen.
// ---------------------------------------------------------------------------
struct GemmArgs {
  const void* A[NSLOT];    // row stride 1024 elements
  const float* W[NSLOT];   // row stride wstride
  long wstride[NSLOT];
  long ooff[NSLOT];        // output offset in SHORT elements
  int abf16[NSLOT];
  int klen[NSLOT];         // K per slot (multiple of 64)
};

__device__ __forceinline__ void gemm_body(const GemmArgs& ga, int N,
                                          short* __restrict__ gps,
                                          int bx, int by, int bz,
                                          ldsT* As, ldsT* Bs) {
  const int z = bz;
  const int ab = ga.abf16[z];
  const float* __restrict__ Af = (const float*)ga.A[z];
  const short* __restrict__ Ah = (const short*)ga.A[z];
  const float* __restrict__ W = ga.W[z];
  const long wstr = ga.wstride[z];
  const int brow = by * 128;
  const int bcol = bx * 128;
  short* __restrict__ out = gps + ga.ooff[z];

  const int tid = threadIdx.x;
  const int wave = tid >> 6, lane = tid & 63;
  const int wr = wave >> 2, wc = wave & 3;   // 2 x 4 wave grid
  const int lrow = lane & 15;
  const int lk8  = (lane >> 4) * 8;

  f32x4 acc[4][2];
#pragma unroll
  for (int m = 0; m < 4; ++m)
#pragma unroll
    for (int n = 0; n < 2; ++n) acc[m][n] = (f32x4){0.f, 0.f, 0.f, 0.f};

  float4 raA[4], rwA[4], raB[4], rwB[4];
  s16x8 rabA[2], rabB[2];

#define LOAD_T(KT, ra_, rab_, rw_)                                             \
  {                                                                            \
    const int kb = (KT) * 64;                                                  \
    if (ab) {                                                                  \
      _Pragma("unroll") for (int i = 0; i < 2; ++i) {                          \
        const int idx = tid + i * 512;                                         \
        const int r = idx >> 3, c8 = (idx & 7) * 8;                            \
        rab_[i] = *(const s16x8*)(Ah + (long)(brow + r) * 1024 + kb + c8);     \
      }                                                                        \
    } else {                                                                   \
      _Pragma("unroll") for (int i = 0; i < 4; ++i) {                          \
        const int idx = tid + i * 512;                                         \
        const int r = idx >> 4, c4 = (idx & 15) * 4;                           \
        ra_[i] = *(const float4*)(Af + (long)(brow + r) * 1024 + kb + c4);     \
      }                                                                        \
    }                                                                          \
    _Pragma("unroll") for (int i = 0; i < 4; ++i) {                            \
      const int idx = tid + i * 512;                                           \
      const int r = idx >> 4, c4 = (idx & 15) * 4;                             \
      rw_[i] = *(const float4*)(W + (long)(bcol + r) * wstr + kb + c4);        \
    }                                                                          \
  }
#define WRITE_T(ra_, rab_, rw_)                                                \
  {                                                                            \
    if (ab) {                                                                  \
      _Pragma("unroll") for (int i = 0; i < 2; ++i) {                          \
        const int idx = tid + i * 512;                                         \
        const int r = idx >> 3, c8 = (idx & 7) * 8;                            \
        *(s16x8*)(&(*As)[r][c8]) = rab_[i];                                    \
      }                                                                        \
    } else {                                                                   \
      _Pragma("unroll") for (int i = 0; i < 4; ++i) {                          \
        const int idx = tid + i * 512;                                         \
        const int r = idx >> 4, c4 = (idx & 15) * 4;                           \
        *(short4*)(&(*As)[r][c4]) = short4{f2bf(ra_[i].x), f2bf(ra_[i].y),     \
                                           f2bf(ra_[i].z), f2bf(ra_[i].w)};    \
      }                                                                        \
    }                                                                          \
    _Pragma("unroll") for (int i = 0; i < 4; ++i) {                            \
      const int idx = tid + i * 512;                                           \
      const int r = idx >> 4, c4 = (idx & 15) * 4;                             \
      *(short4*)(&(*Bs)[r][c4]) = short4{f2bf(rw_[i].x), f2bf(rw_[i].y),       \
                                         f2bf(rw_[i].z), f2bf(rw_[i].w)};      \
    }                                                                          \
  }
#define MFMA_PHASE()                                                           \
  {                                                                            \
    _Pragma("unroll") for (int kk = 0; kk < 64; kk += 32) {                    \
      s16x8 af[4], bf[2];                                                      \
      _Pragma("unroll") for (int m = 0; m < 4; ++m)                            \
        af[m] = *(const s16x8*)(&(*As)[wr * 64 + m * 16 + lrow][kk + lk8]);    \
      _Pragma("unroll") for (int n = 0; n < 2; ++n)                            \
        bf[n] = *(const s16x8*)(&(*Bs)[wc * 32 + n * 16 + lrow][kk + lk8]);    \
      _Pragma("unroll") for (int m = 0; m < 4; ++m)                            \
        _Pragma("unroll") for (int n = 0; n < 2; ++n)                          \
          acc[m][n] = __builtin_amdgcn_mfma_f32_16x16x32_bf16(                 \
              af[m], bf[n], acc[m][n], 0, 0, 0);                               \
    }                                                                          \
  }

  const int ntiles = ga.klen[z] / 64;
  LOAD_T(0, raA, rabA, rwA);
  WRITE_T(raA, rabA, rwA);
  if (ntiles > 1) LOAD_T(1, raB, rabB, rwB);
  __syncthreads();
  int kt = 0;
  for (;;) {
    // even tile: LDS holds kt; B-regs hold kt+1 (in flight)
    MFMA_PHASE();
    if (kt + 1 >= ntiles) break;
    __syncthreads();
    WRITE_T(raB, rabB, rwB);
    if (kt + 2 < ntiles) LOAD_T(kt + 2, raA, rabA, rwA);
    __syncthreads();
    ++kt;
    // odd tile: LDS holds kt; A-regs hold kt+1 (in flight)
    MFMA_PHASE();
    if (kt + 1 >= ntiles) break;
    __syncthreads();
    WRITE_T(raA, rabA, rwA);
    if (kt + 2 < ntiles) LOAD_T(kt + 2, raB, rabB, rwB);
    __syncthreads();
    ++kt;
  }
#undef LOAD_T
#undef WRITE_T
#undef MFMA_PHASE

  // C/D layout: col=lane&15, row=(lane>>4)*4+reg; bf16 partial store
#pragma unroll
  for (int m = 0; m < 4; ++m) {
#pragma unroll
    for (int n = 0; n < 2; ++n) {
      const int col = bcol + wc * 32 + n * 16 + lrow;
#pragma unroll
      for (int r = 0; r < 4; ++r) {
        const int row = brow + wr * 64 + m * 16 + (lane >> 4) * 4 + r;
        out[(long)row * N + col] = f2bf(acc[m][n][r]);
      }
    }
  }
}

// ---------------------------------------------------------------------------
// f32 -> bf16 converter (grid-stride over nb blocks of 512 threads).
// ---------------------------------------------------------------------------
__device__ __forceinline__ void conv_b(const float* __restrict__ src,
                                       __hip_bfloat16* __restrict__ dst,
                                       long nelem, int bid, int nb) {
  const long total = nelem >> 2;
  for (long i = (long)bid * 512 + threadIdx.x; i < total; i += (long)nb * 512) {
    f32x4 v = LD4(src + i * 4);
    *(short4*)((short*)dst + i * 4) =
        short4{f2bf(v[0]), f2bf(v[1]), f2bf(v[2]), f2bf(v[3])};
  }
}

// ---------------------------------------------------------------------------
// fusedA: conv (blocks 0..255) || GEMM (256..575): 10 slots klen=512 =
// 8 att-gate (f32 A) + 2 sh1@lWhh lbase-part (to gpLB slots 0-1).
// ---------------------------------------------------------------------------
__global__ __launch_bounds__(512, 4) void fusedA(
    GemmArgs ga, short* __restrict__ gps,
    const float* __restrict__ vkey, const float* __restrict__ lkey,
    const float* __restrict__ vval, const float* __restrict__ lval,
    __hip_bfloat16* __restrict__ vkb, __hip_bfloat16* __restrict__ lkb,
    __hip_bfloat16* __restrict__ vvb, __hip_bfloat16* __restrict__ lvb) {
  __shared__ __align__(16) union { struct { ldsT As; ldsT Bs; } g; } sm;
  const int bid = blockIdx.x;
  if (bid < 256) {
    conv_b(vkey, vkb, (long)B * NV * 1024, bid, 256);
    conv_b(lkey, lkb, (long)B * NL * 1024, bid, 256);
    conv_b(vval, vvb, (long)B * NV * 1024, bid, 256);
    conv_b(lval, lvb, (long)B * NL * 1024, bid, 256);
  } else {
    const int g = bid - 256;                  // 0..319
    gemm_body(ga, 4096, gps, g & 31, 0, g >> 5, &sm.g.As, &sm.g.Bs);
  }
}

// ---------------------------------------------------------------------------
// att LSTM cell: gates = sum of 8 bf16 partial slots + biases -> h_att
// (f32 + bf16), new_h[0]/new_c[0] to d_out.
// ---------------------------------------------------------------------------
__global__ __launch_bounds__(256) void lstm_att(
    const short* __restrict__ gps, const float* __restrict__ bih,
    const float* __restrict__ bhh, const float* __restrict__ c_prev,
    float* __restrict__ h, __hip_bfloat16* __restrict__ hb,
    float* __restrict__ out) {
  long idx = ((long)blockIdx.x * 256 + threadIdx.x) * 4;
  if (idx >= BD) return;
  int b = (int)(idx >> 10), d = (int)(idx & 1023);
  const long base = (long)b * 4096 + d;
  f32x4 g[4];
#pragma unroll
  for (int gi = 0; gi < 4; ++gi) {
    const long o = base + gi * 1024;
    f32x4 v = LD4(bih + gi * 1024 + d) + LD4(bhh + gi * 1024 + d);
#pragma unroll
    for (int s = 0; s < 8; ++s) v += ld4bf(gps + SGPA + s * SLs + o);
    g[gi] = v;
  }
  f32x4 cp = LD4(c_prev + idx), cc, hh;
#pragma unroll
  for (int j = 0; j < 4; ++j) {
    float ccj = sigf(g[1][j]) * cp[j] + sigf(g[0][j]) * tanhf(g[2][j]);
    cc[j] = ccj;
    hh[j] = sigf(g[3][j]) * tanhf(ccj);
  }
  ST4(h + idx, hh);
  *(short4*)((short*)hb + idx) =
      short4{f2bf(hh[0]), f2bf(hh[1]), f2bf(hh[2]), f2bf(hh[3])};
  ST4(out + O4 + idx, hh);   // new_h[0] == hA/accum == h_att
  ST4(out + O5 + idx, cc);   // new_c[0] == cA/accum == c_att
}

// ---------------------------------------------------------------------------
// attn_mega (proven form): 4 attention steps per b, 1024 threads;
// keys staged into LDS from bf16 cache; bf16 values, ILP ctx; kvs in regs;
// softmax over ORIGINAL keys (slot-uniform update cancels).
// ---------------------------------------------------------------------------
__global__ __launch_bounds__(1024) void attn_mega(
    const float* __restrict__ h_att, const float* __restrict__ kv0,
    const __hip_bfloat16* __restrict__ vkb, const __hip_bfloat16* __restrict__ lkb,
    const __hip_bfloat16* __restrict__ vvb, const __hip_bfloat16* __restrict__ lvb,
    __hip_bfloat16* __restrict__ vctxB, __hip_bfloat16* __restrict__ lctxB,
    float* __restrict__ out_kvs) {
  const int b = blockIdx.x, tid = threadIdx.x;   // tid = d column
  __shared__ short K[56][1024];                  // 112 KB bf16 keys
  __shared__ float q[1024];
  __shared__ float wgt[64];
  const int wave = tid >> 6, lane = tid & 63;

  for (int i = tid; i < 56 * 128; i += 1024) {
    const int r = i >> 7, c8 = (i & 127) * 8;
    const __hip_bfloat16* kp = (r < NV)
        ? vkb + ((long)b * NV + r) * 1024
        : lkb + ((long)b * NL + (r - NV)) * 1024;
    *(s16x8*)(&K[r][c8]) = *(const s16x8*)(kp + c8);
  }

  const float ha = h_att[(long)b * 1024 + tid];
  float kv = kv0[(long)b * 1024 + tid];

  for (int step = 0; step < 4; ++step) {
    q[tid] = ha + kv;
    __syncthreads();
    for (int n = wave; n < NV + NL; n += 16) {
      float s = 0.f;
#pragma unroll
      for (int j = 0; j < 2; ++j) {
        const int base = lane * 8 + j * 512;
        s16x8 k8 = *(const s16x8*)(&K[n][base]);
        f32x4 q0 = *(const f32x4*)(&q[base]);
        f32x4 q1 = *(const f32x4*)(&q[base + 4]);
#pragma unroll
        for (int e = 0; e < 4; ++e) {
          s += bf2f(k8[e]) * q0[e];
          s += bf2f(k8[e + 4]) * q1[e];
        }
      }
      for (int m = 32; m >= 1; m >>= 1) s += __shfl_xor(s, m);
      if (lane == 0) wgt[n] = s * (1.0f / 32.0f);
    }
    __syncthreads();
    if (wave == 0) {
      float x = (lane < NV) ? wgt[lane] : -1e30f;
      float m = x;
      for (int k = 32; k >= 1; k >>= 1) m = fmaxf(m, __shfl_xor(m, k));
      float e = (lane < NV) ? expf(x - m) : 0.f;
      float ssum = e;
      for (int k = 32; k >= 1; k >>= 1) ssum += __shfl_xor(ssum, k);
      if (lane < NV) wgt[lane] = e / ssum;
    } else if (wave == 1) {
      float x = (lane < NL) ? wgt[NV + lane] : -1e30f;
      float m = x;
      for (int k = 32; k >= 1; k >>= 1) m = fmaxf(m, __shfl_xor(m, k));
      float e = (lane < NL) ? expf(x - m) : 0.f;
      float ssum = e;
      for (int k = 32; k >= 1; k >>= 1) ssum += __shfl_xor(ssum, k);
      if (lane < NL) wgt[NV + lane] = e / ssum;
    }
    __syncthreads();
    const __hip_bfloat16* vb = vvb + (long)b * NV * 1024 + tid;
    float a0 = 0.f, a1 = 0.f, a2 = 0.f, a3 = 0.f;
#pragma unroll
    for (int n = 0; n < NV; n += 4) {
      a0 += __bfloat162float(vb[(long)(n + 0) * 1024]) * wgt[n + 0];
      a1 += __bfloat162float(vb[(long)(n + 1) * 1024]) * wgt[n + 1];
      a2 += __bfloat162float(vb[(long)(n + 2) * 1024]) * wgt[n + 2];
      a3 += __bfloat162float(vb[(long)(n + 3) * 1024]) * wgt[n + 3];
    }
    const float vc = (a0 + a1) + (a2 + a3);
    const __hip_bfloat16* lb = lvb + (long)b * NL * 1024 + tid;
    float c0 = 0.f, c1 = 0.f, c2 = 0.f, c3 = 0.f;
#pragma unroll
    for (int n = 0; n < NL; n += 4) {
      c0 += __bfloat162float(lb[(long)(n + 0) * 1024]) * wgt[NV + n + 0];
      c1 += __bfloat162float(lb[(long)(n + 1) * 1024]) * wgt[NV + n + 1];
      c2 += __bfloat162float(lb[(long)(n + 2) * 1024]) * wgt[NV + n + 2];
      c3 += __bfloat162float(lb[(long)(n + 3) * 1024]) * wgt[NV + n + 3];
    }
    const float lc = (c0 + c1) + (c2 + c3);
    const long orow = ((long)step * 128 + b) * 1024 + tid;
    vctxB[orow] = __float2bfloat16(vc);
    lctxB[orow] = __float2bfloat16(lc);
    kv = tanhf(kv + vc + lc);
    __syncthreads();
  }
  out_kvs[(long)b * 1024 + tid] = kv;
}

// ---------------------------------------------------------------------------
// fusedD: batched lang-gates GEMM (blocks 0..511, slots 0-3) ||
//         h_att lbase-part GEMM (blocks 512..575, slots 4-5). Independent.
// ---------------------------------------------------------------------------
__global__ __launch_bounds__(512, 4) void fusedD(GemmArgs ga,
                                                 short* __restrict__ gps) {
  __shared__ __align__(16) union { struct { ldsT As; ldsT Bs; } g; } sm;
  const int bid = blockIdx.x;
  if (bid < 512) {
    gemm_body(ga, 4096, gps, bid & 31, (bid >> 5) & 3, bid >> 7,
              &sm.g.As, &sm.g.Bs);
  } else {
    const int h = bid - 512;                  // 0..63
    gemm_body(ga, 4096, gps, h & 31, 0, 4 + (h >> 5), &sm.g.As, &sm.g.Bs);
  }
}

// ---------------------------------------------------------------------------
// batched lang LSTM (M=512): gates = 4 gpB slots[row] + 4 gpLB slots[b]
// (all bf16) + lbih + lbhh; c_prev = sc1[b].
// ---------------------------------------------------------------------------
__global__ __launch_bounds__(256) void lstm_batch(
    const short* __restrict__ gps, const float* __restrict__ lbih,
    const float* __restrict__ lbhh, const float* __restrict__ sc1,
    float* __restrict__ hB, float* __restrict__ cB) {
  long idx = ((long)blockIdx.x * 256 + threadIdx.x) * 4;
  if (idx >= 512L * 1024) return;
  const int row = (int)(idx >> 10);   // step*128+b
  const int b = row & 127;
  const int d = (int)(idx & 1023);
  const long base = (long)row * 4096 + d;
  const long bbase = (long)b * 4096 + d;
  f32x4 g[4];
#pragma unroll
  for (int gi = 0; gi < 4; ++gi) {
    const long o = gi * 1024;
    f32x4 v = LD4(lbih + gi * 1024 + d) + LD4(lbhh + gi * 1024 + d);
#pragma unroll
    for (int s = 0; s < 4; ++s) v += ld4bf(gps + SGPB + s * SLBs + base + o);
#pragma unroll
    for (int s = 0; s < 4; ++s) v += ld4bf(gps + SGPLB + s * SLs + bbase + o);
    g[gi] = v;
  }
  f32x4 cp = LD4(sc1 + (long)b * 1024 + d), cc, hh;
#pragma unroll
  for (int j = 0; j < 4; ++j) {
    float ccj = sigf(g[1][j]) * cp[j] + sigf(g[0][j]) * tanhf(g[2][j]);
    cc[j] = ccj;
    hh[j] = sigf(g[3][j]) * tanhf(ccj);
  }
  ST4(cB + idx, cc);
  ST4(hB + idx, hh);
}

// ---------------------------------------------------------------------------
// fusedC: conf GEMM (blocks 0..127, slots 0-3) || key-output finalize
// (128..1919): stages S[b][d] = sum_steps hB in LDS, out = key + 0.01*S.
// ---------------------------------------------------------------------------
__global__ __launch_bounds__(512, 4) void fusedC(
    GemmArgs ga, short* __restrict__ gps, const float* __restrict__ hB,
    const __hip_bfloat16* __restrict__ vkb, const __hip_bfloat16* __restrict__ lkb,
    float* __restrict__ out) {
  __shared__ __align__(16) union {
    struct { ldsT As; ldsT Bs; } g;
    struct { float Ssh[1024]; } f;
  } sm;
  const int bid = blockIdx.x;
  if (bid < 128) {
    gemm_body(ga, 1024, gps, bid & 7, (bid >> 3) & 3, bid >> 5,
              &sm.g.As, &sm.g.Bs);
    return;
  }
  const int fb = bid - 128;                 // 0..1791
  const long base = (long)fb * 4096;
  const bool isV = (base < VK);
  const int b = isV ? (int)(base / (NV * 1024))
                    : (int)((base - VK) / (NL * 1024));
  const int tid = threadIdx.x;
  for (int d = tid; d < 1024; d += 512) {
    float s = 0.f;
#pragma unroll
    for (int st = 0; st < 4; ++st) s += hB[((long)st * 128 + b) * 1024 + d];
    sm.f.Ssh[d] = s;
  }
  __syncthreads();
  const long idx = base + (long)tid * 8;
  const int d = (int)(idx & 1023);
  if (isV) {
    s16x8 k8 = *(const s16x8*)((const short*)vkb + idx);
    f32x4 o0, o1;
#pragma unroll
    for (int j = 0; j < 4; ++j) {
      o0[j] = bf2f(k8[j]) + 0.01f * sm.f.Ssh[d + j];
      o1[j] = bf2f(k8[j + 4]) + 0.01f * sm.f.Ssh[d + 4 + j];
    }
    ST4(out + O1 + idx, o0);
    ST4(out + O1 + idx + 4, o1);
  } else {
    const long r = idx - VK;
    s16x8 k8 = *(const s16x8*)((const short*)lkb + r);
    f32x4 o0, o1;
#pragma unroll
    for (int j = 0; j < 4; ++j) {
      o0[j] = bf2f(k8[j]) + 0.01f * sm.f.Ssh[d + j];
      o1[j] = bf2f(k8[j + 4]) + 0.01f * sm.f.Ssh[d + 4 + j];
    }
    ST4(out + O2 + r, o0);
    ST4(out + O2 + r + 4, o1);
  }
}

// ---------------------------------------------------------------------------
// halt_scan: per-b halting recurrence over 4 steps (sums 4 bf16 conf slots).
// ---------------------------------------------------------------------------
__global__ __launch_bounds__(256) void halt_scan(
    const short* __restrict__ gps, const float* __restrict__ cb1,
    const float* __restrict__ W2, const float* __restrict__ b2,
    const float* __restrict__ hB, const float* __restrict__ cB,
    const int* __restrict__ it, float* __restrict__ out) {
  const int b = blockIdx.x, tid = threadIdx.x;
  const int d0 = tid * 4;
  __shared__ float red[256];
  __shared__ float p_sh;
  const f32x4 w4 = LD4(W2 + d0);
  const f32x4 cb = LD4(cb1 + d0);
  f32x4 hl_acc = (f32x4){0.f, 0.f, 0.f, 0.f}, cl_acc = hl_acc;
  float a = 0.f, sel = 1.f, cost = 0.f;

  for (int i = 0; i < 4; ++i) {
    const long o = ((long)i * 128 + b) * 1024 + d0;
    f32x4 rv = cb;
#pragma unroll
    for (int s = 0; s < 4; ++s) rv += ld4bf(gps + SGPC + s * SLCs + o);
    float part = 0.f;
#pragma unroll
    for (int j = 0; j < 4; ++j) part += fmaxf(rv[j], 0.f) * w4[j];
    red[tid] = part;
    __syncthreads();
    for (int s = 128; s > 0; s >>= 1) {
      if (tid < s) red[tid] += red[tid + s];
      __syncthreads();
    }
    if (tid == 0) p_sh = sigf(red[0] + b2[0]);
    __syncthreads();
    const float p = p_sh;
    const float bs = p * (1.f - a) * sel;
    f32x4 hl = LD4(hB + o), cl = LD4(cB + o);
    hl_acc += hl * bs;
    cl_acc += cl * bs;
    cost += (float)(i + 1) * (1.f - p) * sel;
    a += bs;
    sel = (a < 1.f - EPS) ? sel : 0.f;
    __syncthreads();
  }
  const float inv_a = 1.f / a;
  const long ob = (long)b * 1024 + d0;
  ST4(out + ob, hl_acc * inv_a);             // outA
  ST4(out + O4 + BD + ob, hl_acc * inv_a);   // new_h[1]
  ST4(out + O5 + BD + ob, cl_acc * inv_a);   // new_c[1]
  if (tid == 0) out[O3 + b] = cost * ((it[b] > 0) ? 1.f : 0.f);
}

// ---------------------------------------------------------------------------
extern "C" void kernel_launch(void* const* d_in, const int* in_sizes, int n_in,
                              void* d_out, int out_size, void* d_ws, size_t ws_size,
                              hipStream_t stream) {
  const float* xt   = (const float*)d_in[0];
  const int*   it   = (const int*)d_in[1];
  const float* fc   = (const float*)d_in[2];
  const float* vval = (const float*)d_in[3];
  const float* vkey = (const float*)d_in[4];
  const float* lval = (const float*)d_in[5];
  const float* lkey = (const float*)d_in[6];
  const float* kv0  = (const float*)d_in[7];
  const float* sh   = (const float*)d_in[8];   // [2,B,D]
  const float* sc   = (const float*)d_in[9];   // [2,B,D]
  // d_in[10] = max_att_step (4)
  const float* aWih = (const float*)d_in[11];  // [4096,3072]
  const float* aWhh = (const float*)d_in[12];  // [4096,1024]
  const float* abih = (const float*)d_in[13];
  const float* abhh = (const float*)d_in[14];
  const float* lWih = (const float*)d_in[15];  // [4096,3072]
  const float* lWhh = (const float*)d_in[16];  // [4096,1024]
  const float* lbih = (const float*)d_in[17];
  const float* lbhh = (const float*)d_in[18];
  const float* cW1  = (const float*)d_in[19];  // [1024,1024]
  const float* cb1  = (const float*)d_in[20];
  const float* cW2  = (const float*)d_in[21];  // [1,1024]
  const float* cb2  = (const float*)d_in[22];

  float* ws = (float*)d_ws;
  short* gps = (short*)d_ws;
  float* h_att = ws + OFF_HATT;
  float* hB    = ws + OFF_HLB;
  float* cB    = ws + OFF_CLB;
  __hip_bfloat16* vvb  = (__hip_bfloat16*)(ws + OFF_VVB);
  __hip_bfloat16* lvb  = (__hip_bfloat16*)(ws + OFF_LVB);
  __hip_bfloat16* vkb  = (__hip_bfloat16*)(ws + OFF_VKB);
  __hip_bfloat16* lkb  = (__hip_bfloat16*)(ws + OFF_LKB);
  __hip_bfloat16* hatb = (__hip_bfloat16*)(ws + OFF_HATB);
  __hip_bfloat16* vcxb = (__hip_bfloat16*)(ws + OFF_VCXB);
  __hip_bfloat16* lcxb = (__hip_bfloat16*)(ws + OFF_LCXB);

  const float* sh1 = sh + BD;  // state_h[1]
  const float* sc0 = sc;       // state_c[0]
  const float* sc1 = sc + BD;  // state_c[1]
  float* out = (float*)d_out;

  // 1) fusedA: conv (256 blocks) || 10-slot klen=512 GEMM
  {
    GemmArgs ga = {};
    const float* Aops[4] = {sh1, fc, xt, sh};
    const float* Wops[4] = {aWih, aWih + 1024, aWih + 2048, aWhh};
    const long wstrs[4] = {3072, 3072, 3072, 1024};
    for (int p = 0; p < 4; ++p)
      for (int q = 0; q < 2; ++q) {
        const int s = p * 2 + q;
        ga.A[s] = Aops[p] + q * 512;
        ga.W[s] = Wops[p] + q * 512;
        ga.wstride[s] = wstrs[p];
        ga.ooff[s] = SGPA + (long)s * SLs;
        ga.klen[s] = 512;
      }
    for (int q = 0; q < 2; ++q) {           // sh1 @ lWhh halves -> gpLB 0-1
      const int s = 8 + q;
      ga.A[s] = sh1 + q * 512;
      ga.W[s] = lWhh + q * 512;
      ga.wstride[s] = 1024;
      ga.ooff[s] = SGPLB + (long)q * SLs;
      ga.klen[s] = 512;
    }
    fusedA<<<576, 512, 0, stream>>>(ga, gps, vkey, lkey, vval, lval,
                                    vkb, lkb, vvb, lvb);
  }
  // 2) att LSTM -> h_att f32+bf16 (+ new_h[0]/new_c[0] to out)
  lstm_att<<<128, 256, 0, stream>>>(gps, abih, abhh, sc0, h_att, hatb, out);

  // 3) attention (proven 1024-thread LDS-key form)
  attn_mega<<<128, 1024, 0, stream>>>(h_att, kv0, vkb, lkb, vvb, lvb,
                                      vcxb, lcxb, out + O6);

  // 4) fusedD: batched gates GEMM (slots 0-3) || h_att lbase GEMM (slots 4-5)
  {
    GemmArgs ga = {};
    ga.A[0] = vcxb;                                    ga.W[0] = lWih;
    ga.wstride[0] = 3072; ga.abf16[0] = 1;
    ga.ooff[0] = SGPB;             ga.klen[0] = 512;
    ga.A[1] = (const void*)((const short*)vcxb + 512); ga.W[1] = lWih + 512;
    ga.wstride[1] = 3072; ga.abf16[1] = 1;
    ga.ooff[1] = SGPB + SLBs;      ga.klen[1] = 512;
    ga.A[2] = lcxb;                                    ga.W[2] = lWih + 1024;
    ga.wstride[2] = 3072; ga.abf16[2] = 1;
    ga.ooff[2] = SGPB + 2 * SLBs;  ga.klen[2] = 512;
    ga.A[3] = (const void*)((const short*)lcxb + 512); ga.W[3] = lWih + 1536;
    ga.wstride[3] = 3072; ga.abf16[3] = 1;
    ga.ooff[3] = SGPB + 3 * SLBs;  ga.klen[3] = 512;
    for (int q = 0; q < 2; ++q) {           // hatb @ lWih[:,2048:] halves
      const int s = 4 + q;
      ga.A[s] = (const void*)((const short*)hatb + q * 512);
      ga.W[s] = lWih + 2048 + q * 512;
      ga.wstride[s] = 3072;
      ga.abf16[s] = 1;
      ga.ooff[s] = SGPLB + (long)(2 + q) * SLs;
      ga.klen[s] = 512;
    }
    fusedD<<<576, 512, 0, stream>>>(ga, gps);
  }
  // 5) batched lang LSTM (4 gpB slots + 4 gpLB slots + biases)
  lstm_batch<<<512, 256, 0, stream>>>(gps, lbih, lbhh, sc1, hB, cB);

  // 6) fusedC: conf GEMM (128) || key-output finalize (1792)
  {
    GemmArgs ga = {};
    for (int q = 0; q < 4; ++q) {
      ga.A[q] = hB + q * 256;
      ga.W[q] = cW1 + q * 256;
      ga.wstride[q] = 1024;
      ga.ooff[q] = SGPC + (long)q * SLCs;
      ga.klen[q] = 256;
    }
    fusedC<<<1920, 512, 0, stream>>>(ga, gps, hB, vkb, lkb, out);
  }
  // 7) halting scan -> outA, new_h[1], new_c[1], cost
  halt_scan<<<128, 256, 0, stream>>>(gps, cb1, cW2, cb2, hB, cB, it, out);
}

// Round 21
// 151.939 us; speedup vs baseline: 1.3841x; 1.3841x over previous
//
#include <hip/hip_runtime.h>
#include <hip/hip_bf16.h>

// Sizes (fixed by the reference setup)
constexpr int B  = 128;
constexpr int D  = 1024;
constexpr int NV = 36;
constexpr int NL = 20;
constexpr int BD = B * D;              // 131072
constexpr float EPS = 0.01f;
constexpr int NSLOT = 20;

// bf16 partial-slot offsets (in SHORT elements from ws base)
constexpr long SLs  = 524288;                 // [128][4096] bf16 slot
constexpr long SLBs = 2097152;                // [512][4096] bf16 slot
constexpr long SLCs = 524288;                 // [512][1024] bf16 slot
constexpr long SGPA  = 0;                     // 16 att-gate slots
constexpr long SGPLB = SGPA + 16 * SLs;       // 8 lbase slots
constexpr long SGPB  = SGPLB + 8 * SLs;       // 4 lang-gate slots
constexpr long SGPC  = SGPB + 4 * SLBs;       // 4 conf slots

// float offsets (from ws base, after the partial region)
constexpr long FBASE     = (SGPC + 4 * SLCs) / 2;   // floats
constexpr long OFF_HATT  = FBASE;                   // h_att f32 [128][1024]
constexpr long OFF_HLB   = OFF_HATT + BD;           // hB [512][1024]
constexpr long OFF_CLB   = OFF_HLB + 524288;        // cB
constexpr long OFF_VVB   = OFF_CLB + 524288;        // bf16 vval cache
constexpr long OFF_LVB   = OFF_VVB + 2359296;
constexpr long OFF_VKB   = OFF_LVB + 1310720;
constexpr long OFF_LKB   = OFF_VKB + 2359296;
constexpr long OFF_HATB  = OFF_LKB + 1310720;       // bf16 h_att
constexpr long OFF_VCXB  = OFF_HATB + 65536;        // bf16 vctx [512][1024]
constexpr long OFF_LCXB  = OFF_VCXB + 262144;       // bf16 lctx
constexpr long OFF_LWB   = OFF_LCXB + 262144;       // bf16 lWih [4096][3072]
constexpr long OFF_CW1B  = OFF_LWB + 6291456;       // bf16 cW1 [1024][1024]

typedef float f32x4 __attribute__((ext_vector_type(4)));
typedef short s16x8 __attribute__((ext_vector_type(8)));
typedef short ldsT[128][72];

__device__ __forceinline__ float sigf(float x) { return 1.f / (1.f + expf(-x)); }

__device__ __forceinline__ short f2bf(float f) {
  __hip_bfloat16 h = __float2bfloat16(f);
  return *reinterpret_cast<short*>(&h);
}
__device__ __forceinline__ float bf2f(short s) {
  unsigned u = ((unsigned)(unsigned short)s) << 16;
  return __uint_as_float(u);
}
__device__ __forceinline__ f32x4 LD4(const float* p) { return *(const f32x4*)p; }
__device__ __forceinline__ void ST4(float* p, f32x4 v) { *(f32x4*)p = v; }
__device__ __forceinline__ f32x4 ld4bf(const short* p) {
  short4 s = *(const short4*)p;
  return (f32x4){bf2f(s.x), bf2f(s.y), bf2f(s.z), bf2f(s.w)};
}

// d_out section offsets
constexpr long O1 = BD;
constexpr long O2 = O1 + (long)B * NV * D;
constexpr long O3 = O2 + (long)B * NL * D;
constexpr long O4 = O3 + B;
constexpr long O5 = O4 + 2L * BD;
constexpr long O6 = O5 + 2L * BD;
constexpr long O7 = O6 + BD;
constexpr long VK = (long)B * NV * D;
constexpr long LK = (long)B * NL * D;

// ---------------------------------------------------------------------------
// GEMM body (round-18 proven form): tile BM=128 BN=128 BK=64, 512 threads =
// 8 waves (2x4), acc[4][2], single-buffered LDS (36 KB), 1-deep reg prefetch.
// A and W may each be f32 or bf16. Writes bf16 partials. Per-slot klen.
// ---------------------------------------------------------------------------
struct GemmArgs {
  const void* A[NSLOT];    // row stride 1024 elements
  const void* W[NSLOT];    // row stride wstride elements
  long wstride[NSLOT];
  long ooff[NSLOT];        // output offset in SHORT elements
  int abf16[NSLOT];
  int wbf16[NSLOT];
  int klen[NSLOT];         // K per slot (multiple of 64)
};

__device__ __forceinline__ void gemm_body(const GemmArgs& ga, int N,
                                          short* __restrict__ gps,
                                          int bx, int by, int bz,
                                          ldsT* As, ldsT* Bs) {
  const int z = bz;
  const int ab = ga.abf16[z];
  const int wb = ga.wbf16[z];
  const float* __restrict__ Af = (const float*)ga.A[z];
  const short* __restrict__ Ah = (const short*)ga.A[z];
  const float* __restrict__ Wf = (const float*)ga.W[z];
  const short* __restrict__ Wh = (const short*)ga.W[z];
  const long wstr = ga.wstride[z];
  const int brow = by * 128;
  const int bcol = bx * 128;
  short* __restrict__ out = gps + ga.ooff[z];

  const int tid = threadIdx.x;
  const int wave = tid >> 6, lane = tid & 63;
  const int wr = wave >> 2, wc = wave & 3;   // 2 x 4 wave grid
  const int lrow = lane & 15;
  const int lk8  = (lane >> 4) * 8;

  f32x4 acc[4][2];
#pragma unroll
  for (int m = 0; m < 4; ++m)
#pragma unroll
    for (int n = 0; n < 2; ++n) acc[m][n] = (f32x4){0.f, 0.f, 0.f, 0.f};

  float4 ra[4], rw[4];
  s16x8 rab[2], rwb[2];
#define LOAD_TILE(KT)                                                          \
  {                                                                            \
    const int kb = (KT) * 64;                                                  \
    if (ab) {                                                                  \
      _Pragma("unroll") for (int i = 0; i < 2; ++i) {                          \
        const int idx = tid + i * 512;                                         \
        const int r = idx >> 3, c8 = (idx & 7) * 8;                            \
        rab[i] = *(const s16x8*)(Ah + (long)(brow + r) * 1024 + kb + c8);      \
      }                                                                        \
    } else {                                                                   \
      _Pragma("unroll") for (int i = 0; i < 4; ++i) {                          \
        const int idx = tid + i * 512;                                         \
        const int r = idx >> 4, c4 = (idx & 15) * 4;                           \
        ra[i] = *(const float4*)(Af + (long)(brow + r) * 1024 + kb + c4);      \
      }                                                                        \
    }                                                                          \
    if (wb) {                                                                  \
      _Pragma("unroll") for (int i = 0; i < 2; ++i) {                          \
        const int idx = tid + i * 512;                                         \
        const int r = idx >> 3, c8 = (idx & 7) * 8;                            \
        rwb[i] = *(const s16x8*)(Wh + (long)(bcol + r) * wstr + kb + c8);      \
      }                                                                        \
    } else {                                                                   \
      _Pragma("unroll") for (int i = 0; i < 4; ++i) {                          \
        const int idx = tid + i * 512;                                         \
        const int r = idx >> 4, c4 = (idx & 15) * 4;                           \
        rw[i] = *(const float4*)(Wf + (long)(bcol + r) * wstr + kb + c4);      \
      }                                                                        \
    }                                                                          \
  }
#define WRITE_TILE()                                                           \
  {                                                                            \
    if (ab) {                                                                  \
      _Pragma("unroll") for (int i = 0; i < 2; ++i) {                          \
        const int idx = tid + i * 512;                                         \
        const int r = idx >> 3, c8 = (idx & 7) * 8;                            \
        *(s16x8*)(&(*As)[r][c8]) = rab[i];                                     \
      }                                                                        \
    } else {                                                                   \
      _Pragma("unroll") for (int i = 0; i < 4; ++i) {                          \
        const int idx = tid + i * 512;                                         \
        const int r = idx >> 4, c4 = (idx & 15) * 4;                           \
        *(short4*)(&(*As)[r][c4]) =                                            \
            short4{f2bf(ra[i].x), f2bf(ra[i].y), f2bf(ra[i].z), f2bf(ra[i].w)};\
      }                                                                        \
    }                                                                          \
    if (wb) {                                                                  \
      _Pragma("unroll") for (int i = 0; i < 2; ++i) {                          \
        const int idx = tid + i * 512;                                         \
        const int r = idx >> 3, c8 = (idx & 7) * 8;                            \
        *(s16x8*)(&(*Bs)[r][c8]) = rwb[i];                                     \
      }                                                                        \
    } else {                                                                   \
      _Pragma("unroll") for (int i = 0; i < 4; ++i) {                          \
        const int idx = tid + i * 512;                                         \
        const int r = idx >> 4, c4 = (idx & 15) * 4;                           \
        *(short4*)(&(*Bs)[r][c4]) =                                            \
            short4{f2bf(rw[i].x), f2bf(rw[i].y), f2bf(rw[i].z), f2bf(rw[i].w)};\
      }                                                                        \
    }                                                                          \
  }

  const int ntiles = ga.klen[z] / 64;
  LOAD_TILE(0);
  WRITE_TILE();
  __syncthreads();
  for (int kt = 0; kt < ntiles; ++kt) {
    const bool more = (kt + 1 < ntiles);
    if (more) LOAD_TILE(kt + 1);  // reg-staged; in flight during MFMA phase
#pragma unroll
    for (int kk = 0; kk < 64; kk += 32) {
      s16x8 af[4], bf[2];
#pragma unroll
      for (int m = 0; m < 4; ++m)
        af[m] = *(const s16x8*)(&(*As)[wr * 64 + m * 16 + lrow][kk + lk8]);
#pragma unroll
      for (int n = 0; n < 2; ++n)
        bf[n] = *(const s16x8*)(&(*Bs)[wc * 32 + n * 16 + lrow][kk + lk8]);
#pragma unroll
      for (int m = 0; m < 4; ++m)
#pragma unroll
        for (int n = 0; n < 2; ++n)
          acc[m][n] = __builtin_amdgcn_mfma_f32_16x16x32_bf16(
              af[m], bf[n], acc[m][n], 0, 0, 0);
    }
    if (more) {
      __syncthreads();   // all waves done reading the buffer
      WRITE_TILE();
      __syncthreads();   // buffer ready for next MFMA phase
    }
  }
#undef LOAD_TILE
#undef WRITE_TILE

  // C/D layout: col=lane&15, row=(lane>>4)*4+reg; bf16 partial store
#pragma unroll
  for (int m = 0; m < 4; ++m) {
#pragma unroll
    for (int n = 0; n < 2; ++n) {
      const int col = bcol + wc * 32 + n * 16 + lrow;
#pragma unroll
      for (int r = 0; r < 4; ++r) {
        const int row = brow + wr * 64 + m * 16 + (lane >> 4) * 4 + r;
        out[(long)row * N + col] = f2bf(acc[m][n][r]);
      }
    }
  }
}

// ---------------------------------------------------------------------------
// f32 -> bf16 converter (grid-stride over nb blocks of 512 threads).
// ---------------------------------------------------------------------------
__device__ __forceinline__ void conv_b(const float* __restrict__ src,
                                       __hip_bfloat16* __restrict__ dst,
                                       long nelem, int bid, int nb) {
  const long total = nelem >> 2;
  for (long i = (long)bid * 512 + threadIdx.x; i < total; i += (long)nb * 512) {
    f32x4 v = LD4(src + i * 4);
    *(short4*)((short*)dst + i * 4) =
        short4{f2bf(v[0]), f2bf(v[1]), f2bf(v[2]), f2bf(v[3])};
  }
}

// ---------------------------------------------------------------------------
// fusedA: conv (blocks 0..255: K/V + lWih + cW1 -> bf16) || GEMM (256..895):
// 20 slots klen=256 = 16 att-gate (f32 A,W) + 4 sh1@lWhh lbase-part.
// ---------------------------------------------------------------------------
__global__ __launch_bounds__(512, 4) void fusedA(
    GemmArgs ga, short* __restrict__ gps,
    const float* __restrict__ vkey, const float* __restrict__ lkey,
    const float* __restrict__ vval, const float* __restrict__ lval,
    const float* __restrict__ lWih, const float* __restrict__ cW1,
    __hip_bfloat16* __restrict__ vkb, __hip_bfloat16* __restrict__ lkb,
    __hip_bfloat16* __restrict__ vvb, __hip_bfloat16* __restrict__ lvb,
    __hip_bfloat16* __restrict__ lwb, __hip_bfloat16* __restrict__ cw1b) {
  __shared__ __align__(16) union { struct { ldsT As; ldsT Bs; } g; } sm;
  const int bid = blockIdx.x;
  if (bid < 256) {
    conv_b(vkey, vkb, (long)B * NV * 1024, bid, 256);
    conv_b(lkey, lkb, (long)B * NL * 1024, bid, 256);
    conv_b(vval, vvb, (long)B * NV * 1024, bid, 256);
    conv_b(lval, lvb, (long)B * NL * 1024, bid, 256);
    conv_b(lWih, lwb, 4096L * 3072, bid, 256);
    conv_b(cW1, cw1b, 1024L * 1024, bid, 256);
  } else {
    const int g = bid - 256;                  // 0..639
    gemm_body(ga, 4096, gps, g & 31, 0, g >> 5, &sm.g.As, &sm.g.Bs);
  }
}

// ---------------------------------------------------------------------------
// att LSTM cell: gates = sum of 16 bf16 partial slots + biases -> h_att
// (f32 + bf16), new_h[0]/new_c[0] to d_out.
// ---------------------------------------------------------------------------
__global__ __launch_bounds__(256) void lstm_att(
    const short* __restrict__ gps, const float* __restrict__ bih,
    const float* __restrict__ bhh, const float* __restrict__ c_prev,
    float* __restrict__ h, __hip_bfloat16* __restrict__ hb,
    float* __restrict__ out) {
  long idx = ((long)blockIdx.x * 256 + threadIdx.x) * 4;
  if (idx >= BD) return;
  int b = (int)(idx >> 10), d = (int)(idx & 1023);
  const long base = (long)b * 4096 + d;
  f32x4 g[4];
#pragma unroll
  for (int gi = 0; gi < 4; ++gi) {
    const long o = base + gi * 1024;
    f32x4 v = LD4(bih + gi * 1024 + d) + LD4(bhh + gi * 1024 + d);
#pragma unroll
    for (int s = 0; s < 16; ++s) v += ld4bf(gps + SGPA + s * SLs + o);
    g[gi] = v;
  }
  f32x4 cp = LD4(c_prev + idx), cc, hh;
#pragma unroll
  for (int j = 0; j < 4; ++j) {
    float ccj = sigf(g[1][j]) * cp[j] + sigf(g[0][j]) * tanhf(g[2][j]);
    cc[j] = ccj;
    hh[j] = sigf(g[3][j]) * tanhf(ccj);
  }
  ST4(h + idx, hh);
  *(short4*)((short*)hb + idx) =
      short4{f2bf(hh[0]), f2bf(hh[1]), f2bf(hh[2]), f2bf(hh[3])};
  ST4(out + O4 + idx, hh);   // new_h[0] == hA/accum == h_att
  ST4(out + O5 + idx, cc);   // new_c[0] == cA/accum == c_att
}

// ---------------------------------------------------------------------------
// attn_mega (proven form): 4 attention steps per b, 1024 threads;
// keys staged into LDS from bf16 cache; bf16 values, ILP ctx; kvs in regs;
// softmax over ORIGINAL keys (slot-uniform update cancels).
// ---------------------------------------------------------------------------
__global__ __launch_bounds__(1024) void attn_mega(
    const float* __restrict__ h_att, const float* __restrict__ kv0,
    const __hip_bfloat16* __restrict__ vkb, const __hip_bfloat16* __restrict__ lkb,
    const __hip_bfloat16* __restrict__ vvb, const __hip_bfloat16* __restrict__ lvb,
    __hip_bfloat16* __restrict__ vctxB, __hip_bfloat16* __restrict__ lctxB,
    float* __restrict__ out_kvs) {
  const int b = blockIdx.x, tid = threadIdx.x;   // tid = d column
  __shared__ short K[56][1024];                  // 112 KB bf16 keys
  __shared__ float q[1024];
  __shared__ float wgt[64];
  const int wave = tid >> 6, lane = tid & 63;

  for (int i = tid; i < 56 * 128; i += 1024) {
    const int r = i >> 7, c8 = (i & 127) * 8;
    const __hip_bfloat16* kp = (r < NV)
        ? vkb + ((long)b * NV + r) * 1024
        : lkb + ((long)b * NL + (r - NV)) * 1024;
    *(s16x8*)(&K[r][c8]) = *(const s16x8*)(kp + c8);
  }

  const float ha = h_att[(long)b * 1024 + tid];
  float kv = kv0[(long)b * 1024 + tid];

  for (int step = 0; step < 4; ++step) {
    q[tid] = ha + kv;
    __syncthreads();
    for (int n = wave; n < NV + NL; n += 16) {
      float s = 0.f;
#pragma unroll
      for (int j = 0; j < 2; ++j) {
        const int base = lane * 8 + j * 512;
        s16x8 k8 = *(const s16x8*)(&K[n][base]);
        f32x4 q0 = *(const f32x4*)(&q[base]);
        f32x4 q1 = *(const f32x4*)(&q[base + 4]);
#pragma unroll
        for (int e = 0; e < 4; ++e) {
          s += bf2f(k8[e]) * q0[e];
          s += bf2f(k8[e + 4]) * q1[e];
        }
      }
      for (int m = 32; m >= 1; m >>= 1) s += __shfl_xor(s, m);
      if (lane == 0) wgt[n] = s * (1.0f / 32.0f);
    }
    __syncthreads();
    if (wave == 0) {
      float x = (lane < NV) ? wgt[lane] : -1e30f;
      float m = x;
      for (int k = 32; k >= 1; k >>= 1) m = fmaxf(m, __shfl_xor(m, k));
      float e = (lane < NV) ? expf(x - m) : 0.f;
      float ssum = e;
      for (int k = 32; k >= 1; k >>= 1) ssum += __shfl_xor(ssum, k);
      if (lane < NV) wgt[lane] = e / ssum;
    } else if (wave == 1) {
      float x = (lane < NL) ? wgt[NV + lane] : -1e30f;
      float m = x;
      for (int k = 32; k >= 1; k >>= 1) m = fmaxf(m, __shfl_xor(m, k));
      float e = (lane < NL) ? expf(x - m) : 0.f;
      float ssum = e;
      for (int k = 32; k >= 1; k >>= 1) ssum += __shfl_xor(ssum, k);
      if (lane < NL) wgt[NV + lane] = e / ssum;
    }
    __syncthreads();
    const __hip_bfloat16* vb = vvb + (long)b * NV * 1024 + tid;
    float a0 = 0.f, a1 = 0.f, a2 = 0.f, a3 = 0.f;
#pragma unroll
    for (int n = 0; n < NV; n += 4) {
      a0 += __bfloat162float(vb[(long)(n + 0) * 1024]) * wgt[n + 0];
      a1 += __bfloat162float(vb[(long)(n + 1) * 1024]) * wgt[n + 1];
      a2 += __bfloat162float(vb[(long)(n + 2) * 1024]) * wgt[n + 2];
      a3 += __bfloat162float(vb[(long)(n + 3) * 1024]) * wgt[n + 3];
    }
    const float vc = (a0 + a1) + (a2 + a3);
    const __hip_bfloat16* lb = lvb + (long)b * NL * 1024 + tid;
    float c0 = 0.f, c1 = 0.f, c2 = 0.f, c3 = 0.f;
#pragma unroll
    for (int n = 0; n < NL; n += 4) {
      c0 += __bfloat162float(lb[(long)(n + 0) * 1024]) * wgt[NV + n + 0];
      c1 += __bfloat162float(lb[(long)(n + 1) * 1024]) * wgt[NV + n + 1];
      c2 += __bfloat162float(lb[(long)(n + 2) * 1024]) * wgt[NV + n + 2];
      c3 += __bfloat162float(lb[(long)(n + 3) * 1024]) * wgt[NV + n + 3];
    }
    const float lc = (c0 + c1) + (c2 + c3);
    const long orow = ((long)step * 128 + b) * 1024 + tid;
    vctxB[orow] = __float2bfloat16(vc);
    lctxB[orow] = __float2bfloat16(lc);
    kv = tanhf(kv + vc + lc);
    __syncthreads();
  }
  out_kvs[(long)b * 1024 + tid] = kv;
}

// ---------------------------------------------------------------------------
// fusedD: batched lang-gates GEMM (blocks 0..511, slots 0-3, bf16 A+W) ||
//         h_att lbase-part GEMM (blocks 512..639, slots 4-7, bf16 A+W).
// ---------------------------------------------------------------------------
__global__ __launch_bounds__(512, 4) void fusedD(GemmArgs ga,
                                                 short* __restrict__ gps) {
  __shared__ __align__(16) union { struct { ldsT As; ldsT Bs; } g; } sm;
  const int bid = blockIdx.x;
  if (bid < 512) {
    gemm_body(ga, 4096, gps, bid & 31, (bid >> 5) & 3, bid >> 7,
              &sm.g.As, &sm.g.Bs);
  } else {
    const int h = bid - 512;                  // 0..127
    gemm_body(ga, 4096, gps, h & 31, 0, 4 + (h >> 5), &sm.g.As, &sm.g.Bs);
  }
}

// ---------------------------------------------------------------------------
// batched lang LSTM (M=512): gates = 4 gpB slots[row] + 8 gpLB slots[b]
// (all bf16) + lbih + lbhh; c_prev = sc1[b].
// ---------------------------------------------------------------------------
__global__ __launch_bounds__(256) void lstm_batch(
    const short* __restrict__ gps, const float* __restrict__ lbih,
    const float* __restrict__ lbhh, const float* __restrict__ sc1,
    float* __restrict__ hB, float* __restrict__ cB) {
  long idx = ((long)blockIdx.x * 256 + threadIdx.x) * 4;
  if (idx >= 512L * 1024) return;
  const int row = (int)(idx >> 10);   // step*128+b
  const int b = row & 127;
  const int d = (int)(idx & 1023);
  const long base = (long)row * 4096 + d;
  const long bbase = (long)b * 4096 + d;
  f32x4 g[4];
#pragma unroll
  for (int gi = 0; gi < 4; ++gi) {
    const long o = gi * 1024;
    f32x4 v = LD4(lbih + gi * 1024 + d) + LD4(lbhh + gi * 1024 + d);
#pragma unroll
    for (int s = 0; s < 4; ++s) v += ld4bf(gps + SGPB + s * SLBs + base + o);
#pragma unroll
    for (int s = 0; s < 8; ++s) v += ld4bf(gps + SGPLB + s * SLs + bbase + o);
    g[gi] = v;
  }
  f32x4 cp = LD4(sc1 + (long)b * 1024 + d), cc, hh;
#pragma unroll
  for (int j = 0; j < 4; ++j) {
    float ccj = sigf(g[1][j]) * cp[j] + sigf(g[0][j]) * tanhf(g[2][j]);
    cc[j] = ccj;
    hh[j] = sigf(g[3][j]) * tanhf(ccj);
  }
  ST4(cB + idx, cc);
  ST4(hB + idx, hh);
}

// ---------------------------------------------------------------------------
// fusedC: conf GEMM (blocks 0..127, slots 0-3, bf16 W) || key-output finalize
// (128..1919): stages S[b][d] = sum_steps hB in LDS, out = key + 0.01*S.
// ---------------------------------------------------------------------------
__global__ __launch_bounds__(512, 4) void fusedC(
    GemmArgs ga, short* __restrict__ gps, const float* __restrict__ hB,
    const __hip_bfloat16* __restrict__ vkb, const __hip_bfloat16* __restrict__ lkb,
    float* __restrict__ out) {
  __shared__ __align__(16) union {
    struct { ldsT As; ldsT Bs; } g;
    struct { float Ssh[1024]; } f;
  } sm;
  const int bid = blockIdx.x;
  if (bid < 128) {
    gemm_body(ga, 1024, gps, bid & 7, (bid >> 3) & 3, bid >> 5,
              &sm.g.As, &sm.g.Bs);
    return;
  }
  const int fb = bid - 128;                 // 0..1791
  const long base = (long)fb * 4096;
  const bool isV = (base < VK);
  const int b = isV ? (int)(base / (NV * 1024))
                    : (int)((base - VK) / (NL * 1024));
  const int tid = threadIdx.x;
  for (int d = tid; d < 1024; d += 512) {
    float s = 0.f;
#pragma unroll
    for (int st = 0; st < 4; ++st) s += hB[((long)st * 128 + b) * 1024 + d];
    sm.f.Ssh[d] = s;
  }
  __syncthreads();
  const long idx = base + (long)tid * 8;
  const int d = (int)(idx & 1023);
  if (isV) {
    s16x8 k8 = *(const s16x8*)((const short*)vkb + idx);
    f32x4 o0, o1;
#pragma unroll
    for (int j = 0; j < 4; ++j) {
      o0[j] = bf2f(k8[j]) + 0.01f * sm.f.Ssh[d + j];
      o1[j] = bf2f(k8[j + 4]) + 0.01f * sm.f.Ssh[d + 4 + j];
    }
    ST4(out + O1 + idx, o0);
    ST4(out + O1 + idx + 4, o1);
  } else {
    const long r = idx - VK;
    s16x8 k8 = *(const s16x8*)((const short*)lkb + r);
    f32x4 o0, o1;
#pragma unroll
    for (int j = 0; j < 4; ++j) {
      o0[j] = bf2f(k8[j]) + 0.01f * sm.f.Ssh[d + j];
      o1[j] = bf2f(k8[j + 4]) + 0.01f * sm.f.Ssh[d + 4 + j];
    }
    ST4(out + O2 + r, o0);
    ST4(out + O2 + r + 4, o1);
  }
}

// ---------------------------------------------------------------------------
// halt_scan: per-b halting recurrence over 4 steps (sums 4 bf16 conf slots).
// ---------------------------------------------------------------------------
__global__ __launch_bounds__(256) void halt_scan(
    const short* __restrict__ gps, const float* __restrict__ cb1,
    const float* __restrict__ W2, const float* __restrict__ b2,
    const float* __restrict__ hB, const float* __restrict__ cB,
    const int* __restrict__ it, float* __restrict__ out) {
  const int b = blockIdx.x, tid = threadIdx.x;
  const int d0 = tid * 4;
  __shared__ float red[256];
  __shared__ float p_sh;
  const f32x4 w4 = LD4(W2 + d0);
  const f32x4 cb = LD4(cb1 + d0);
  f32x4 hl_acc = (f32x4){0.f, 0.f, 0.f, 0.f}, cl_acc = hl_acc;
  float a = 0.f, sel = 1.f, cost = 0.f;

  for (int i = 0; i < 4; ++i) {
    const long o = ((long)i * 128 + b) * 1024 + d0;
    f32x4 rv = cb;
#pragma unroll
    for (int s = 0; s < 4; ++s) rv += ld4bf(gps + SGPC + s * SLCs + o);
    float part = 0.f;
#pragma unroll
    for (int j = 0; j < 4; ++j) part += fmaxf(rv[j], 0.f) * w4[j];
    red[tid] = part;
    __syncthreads();
    for (int s = 128; s > 0; s >>= 1) {
      if (tid < s) red[tid] += red[tid + s];
      __syncthreads();
    }
    if (tid == 0) p_sh = sigf(red[0] + b2[0]);
    __syncthreads();
    const float p = p_sh;
    const float bs = p * (1.f - a) * sel;
    f32x4 hl = LD4(hB + o), cl = LD4(cB + o);
    hl_acc += hl * bs;
    cl_acc += cl * bs;
    cost += (float)(i + 1) * (1.f - p) * sel;
    a += bs;
    sel = (a < 1.f - EPS) ? sel : 0.f;
    __syncthreads();
  }
  const float inv_a = 1.f / a;
  const long ob = (long)b * 1024 + d0;
  ST4(out + ob, hl_acc * inv_a);             // outA
  ST4(out + O4 + BD + ob, hl_acc * inv_a);   // new_h[1]
  ST4(out + O5 + BD + ob, cl_acc * inv_a);   // new_c[1]
  if (tid == 0) out[O3 + b] = cost * ((it[b] > 0) ? 1.f : 0.f);
}

// ---------------------------------------------------------------------------
extern "C" void kernel_launch(void* const* d_in, const int* in_sizes, int n_in,
                              void* d_out, int out_size, void* d_ws, size_t ws_size,
                              hipStream_t stream) {
  const float* xt   = (const float*)d_in[0];
  const int*   it   = (const int*)d_in[1];
  const float* fc   = (const float*)d_in[2];
  const float* vval = (const float*)d_in[3];
  const float* vkey = (const float*)d_in[4];
  const float* lval = (const float*)d_in[5];
  const float* lkey = (const float*)d_in[6];
  const float* kv0  = (const float*)d_in[7];
  const float* sh   = (const float*)d_in[8];   // [2,B,D]
  const float* sc   = (const float*)d_in[9];   // [2,B,D]
  // d_in[10] = max_att_step (4)
  const float* aWih = (const float*)d_in[11];  // [4096,3072]
  const float* aWhh = (const float*)d_in[12];  // [4096,1024]
  const float* abih = (const float*)d_in[13];
  const float* abhh = (const float*)d_in[14];
  const float* lWih = (const float*)d_in[15];  // [4096,3072]
  const float* lWhh = (const float*)d_in[16];  // [4096,1024]
  const float* lbih = (const float*)d_in[17];
  const float* lbhh = (const float*)d_in[18];
  const float* cW1  = (const float*)d_in[19];  // [1024,1024]
  const float* cb1  = (const float*)d_in[20];
  const float* cW2  = (const float*)d_in[21];  // [1,1024]
  const float* cb2  = (const float*)d_in[22];

  float* ws = (float*)d_ws;
  short* gps = (short*)d_ws;
  float* h_att = ws + OFF_HATT;
  float* hB    = ws + OFF_HLB;
  float* cB    = ws + OFF_CLB;
  __hip_bfloat16* vvb  = (__hip_bfloat16*)(ws + OFF_VVB);
  __hip_bfloat16* lvb  = (__hip_bfloat16*)(ws + OFF_LVB);
  __hip_bfloat16* vkb  = (__hip_bfloat16*)(ws + OFF_VKB);
  __hip_bfloat16* lkb  = (__hip_bfloat16*)(ws + OFF_LKB);
  __hip_bfloat16* hatb = (__hip_bfloat16*)(ws + OFF_HATB);
  __hip_bfloat16* vcxb = (__hip_bfloat16*)(ws + OFF_VCXB);
  __hip_bfloat16* lcxb = (__hip_bfloat16*)(ws + OFF_LCXB);
  __hip_bfloat16* lwb  = (__hip_bfloat16*)(ws + OFF_LWB);
  __hip_bfloat16* cw1b = (__hip_bfloat16*)(ws + OFF_CW1B);

  const float* sh1 = sh + BD;  // state_h[1]
  const float* sc0 = sc;       // state_c[0]
  const float* sc1 = sc + BD;  // state_c[1]
  float* out = (float*)d_out;

  // 1) fusedA: conv (K/V + lWih + cW1 -> bf16) || 20-slot klen=256 GEMM
  {
    GemmArgs ga = {};
    const float* Aops[4] = {sh1, fc, xt, sh};
    const float* Wops[4] = {aWih, aWih + 1024, aWih + 2048, aWhh};
    const long wstrs[4] = {3072, 3072, 3072, 1024};
    for (int p = 0; p < 4; ++p)
      for (int q = 0; q < 4; ++q) {
        const int s = p * 4 + q;
        ga.A[s] = Aops[p] + q * 256;
        ga.W[s] = Wops[p] + q * 256;
        ga.wstride[s] = wstrs[p];
        ga.ooff[s] = SGPA + (long)s * SLs;
        ga.klen[s] = 256;
      }
    for (int q = 0; q < 4; ++q) {           // sh1 @ lWhh quarters -> gpLB 0-3
      const int s = 16 + q;
      ga.A[s] = sh1 + q * 256;
      ga.W[s] = lWhh + q * 256;
      ga.wstride[s] = 1024;
      ga.ooff[s] = SGPLB + (long)q * SLs;
      ga.klen[s] = 256;
    }
    fusedA<<<896, 512, 0, stream>>>(ga, gps, vkey, lkey, vval, lval, lWih, cW1,
                                    vkb, lkb, vvb, lvb, lwb, cw1b);
  }
  // 2) att LSTM -> h_att f32+bf16 (+ new_h[0]/new_c[0] to out)
  lstm_att<<<128, 256, 0, stream>>>(gps, abih, abhh, sc0, h_att, hatb, out);

  // 3) attention (proven 1024-thread LDS-key form)
  attn_mega<<<128, 1024, 0, stream>>>(h_att, kv0, vkb, lkb, vvb, lvb,
                                      vcxb, lcxb, out + O6);

  // 4) fusedD: batched gates GEMM (slots 0-3) || h_att lbase GEMM (slots 4-7)
  //    All W from the bf16 lWih cache (stride 3072 shorts).
  {
    GemmArgs ga = {};
    const short* lw = (const short*)lwb;
    ga.A[0] = vcxb;                                    ga.W[0] = lw;
    ga.wstride[0] = 3072; ga.abf16[0] = 1; ga.wbf16[0] = 1;
    ga.ooff[0] = SGPB;             ga.klen[0] = 512;
    ga.A[1] = (const void*)((const short*)vcxb + 512); ga.W[1] = lw + 512;
    ga.wstride[1] = 3072; ga.abf16[1] = 1; ga.wbf16[1] = 1;
    ga.ooff[1] = SGPB + SLBs;      ga.klen[1] = 512;
    ga.A[2] = lcxb;                                    ga.W[2] = lw + 1024;
    ga.wstride[2] = 3072; ga.abf16[2] = 1; ga.wbf16[2] = 1;
    ga.ooff[2] = SGPB + 2 * SLBs;  ga.klen[2] = 512;
    ga.A[3] = (const void*)((const short*)lcxb + 512); ga.W[3] = lw + 1536;
    ga.wstride[3] = 3072; ga.abf16[3] = 1; ga.wbf16[3] = 1;
    ga.ooff[3] = SGPB + 3 * SLBs;  ga.klen[3] = 512;
    for (int q = 0; q < 4; ++q) {           // hatb @ lWih[:,2048:] quarters
      const int s = 4 + q;
      ga.A[s] = (const void*)((const short*)hatb + q * 256);
      ga.W[s] = lw + 2048 + q * 256;
      ga.wstride[s] = 3072;
      ga.abf16[s] = 1;
      ga.wbf16[s] = 1;
      ga.ooff[s] = SGPLB + (long)(4 + q) * SLs;
      ga.klen[s] = 256;
    }
    fusedD<<<640, 512, 0, stream>>>(ga, gps);
  }
  // 5) batched lang LSTM (4 gpB slots + 8 gpLB slots + biases)
  lstm_batch<<<512, 256, 0, stream>>>(gps, lbih, lbhh, sc1, hB, cB);

  // 6) fusedC: conf GEMM (128, bf16 W) || key-output finalize (1792)
  {
    GemmArgs ga = {};
    for (int q = 0; q < 4; ++q) {
      ga.A[q] = hB + q * 256;
      ga.W[q] = (const short*)cw1b + q * 256;
      ga.wstride[q] = 1024;
      ga.wbf16[q] = 1;
      ga.ooff[q] = SGPC + (long)q * SLCs;
      ga.klen[q] = 256;
    }
    fusedC<<<1920, 512, 0, stream>>>(ga, gps, hB, vkb, lkb, out);
  }
  // 7) halting scan -> outA, new_h[1], new_c[1], cost
  halt_scan<<<128, 256, 0, stream>>>(gps, cb1, cW2, cb2, hB, cB, it, out);
}

// Round 22
// 133.059 us; speedup vs baseline: 1.5804x; 1.1419x over previous
//
#include <hip/hip_runtime.h>
#include <hip/hip_bf16.h>

// Sizes (fixed by the reference setup)
constexpr int B  = 128;
constexpr int D  = 1024;
constexpr int NV = 36;
constexpr int NL = 20;
constexpr int BD = B * D;              // 131072
constexpr float EPS = 0.01f;
constexpr int NSLOT = 20;

// bf16 partial-slot offsets (in SHORT elements from ws base)
constexpr long SLs  = 524288;                 // [128][4096] bf16 slot
constexpr long SLBs = 2097152;                // [512][4096] bf16 slot
constexpr long SLCs = 524288;                 // [512][1024] bf16 slot
constexpr long SGPA  = 0;                     // 16 att-gate slots
constexpr long SGPLB = SGPA + 16 * SLs;       // 8 lbase slots
constexpr long SGPB  = SGPLB + 8 * SLs;       // 4 lang-gate slots
constexpr long SGPC  = SGPB + 4 * SLBs;       // 4 conf slots

// float offsets (from ws base, after the partial region)
constexpr long FBASE     = (SGPC + 4 * SLCs) / 2;   // floats
constexpr long OFF_HATT  = FBASE;                   // h_att f32 [128][1024]
constexpr long OFF_HLB   = OFF_HATT + BD;           // hB [512][1024]
constexpr long OFF_CLB   = OFF_HLB + 524288;        // cB
constexpr long OFF_VVB   = OFF_CLB + 524288;        // bf16 vval cache
constexpr long OFF_LVB   = OFF_VVB + 2359296;
constexpr long OFF_VKB   = OFF_LVB + 1310720;
constexpr long OFF_LKB   = OFF_VKB + 2359296;
constexpr long OFF_HATB  = OFF_LKB + 1310720;       // bf16 h_att
constexpr long OFF_VCXB  = OFF_HATB + 65536;        // bf16 vctx [512][1024]
constexpr long OFF_LCXB  = OFF_VCXB + 262144;       // bf16 lctx

typedef float f32x4 __attribute__((ext_vector_type(4)));
typedef short s16x8 __attribute__((ext_vector_type(8)));
typedef short ldsT[128][72];

__device__ __forceinline__ float sigf(float x) { return 1.f / (1.f + expf(-x)); }

__device__ __forceinline__ short f2bf(float f) {
  __hip_bfloat16 h = __float2bfloat16(f);
  return *reinterpret_cast<short*>(&h);
}
__device__ __forceinline__ float bf2f(short s) {
  unsigned u = ((unsigned)(unsigned short)s) << 16;
  return __uint_as_float(u);
}
__device__ __forceinline__ f32x4 LD4(const float* p) { return *(const f32x4*)p; }
__device__ __forceinline__ void ST4(float* p, f32x4 v) { *(f32x4*)p = v; }
__device__ __forceinline__ f32x4 ld4bf(const short* p) {
  short4 s = *(const short4*)p;
  return (f32x4){bf2f(s.x), bf2f(s.y), bf2f(s.z), bf2f(s.w)};
}

// d_out section offsets
constexpr long O1 = BD;
constexpr long O2 = O1 + (long)B * NV * D;
constexpr long O3 = O2 + (long)B * NL * D;
constexpr long O4 = O3 + B;
constexpr long O5 = O4 + 2L * BD;
constexpr long O6 = O5 + 2L * BD;
constexpr long O7 = O6 + BD;
constexpr long VK = (long)B * NV * D;
constexpr long LK = (long)B * NL * D;

// ---------------------------------------------------------------------------
// GEMM body (round-18 proven form): tile BM=128 BN=128 BK=64, 512 threads =
// 8 waves (2x4), acc[4][2], single-buffered LDS (36 KB), 1-deep reg prefetch.
// Writes bf16 partials. A may be f32 or bf16. Per-slot klen.
// ---------------------------------------------------------------------------
struct GemmArgs {
  const void* A[NSLOT];    // row stride 1024 elements
  const float* W[NSLOT];   // row stride wstride
  long wstride[NSLOT];
  long ooff[NSLOT];        // output offset in SHORT elements
  int abf16[NSLOT];
  int klen[NSLOT];         // K per slot (multiple of 64)
};

__device__ __forceinline__ void gemm_body(const GemmArgs& ga, int N,
                                          short* __restrict__ gps,
                                          int bx, int by, int bz,
                                          ldsT* As, ldsT* Bs) {
  const int z = bz;
  const int ab = ga.abf16[z];
  const float* __restrict__ Af = (const float*)ga.A[z];
  const short* __restrict__ Ah = (const short*)ga.A[z];
  const float* __restrict__ W = ga.W[z];
  const long wstr = ga.wstride[z];
  const int brow = by * 128;
  const int bcol = bx * 128;
  short* __restrict__ out = gps + ga.ooff[z];

  const int tid = threadIdx.x;
  const int wave = tid >> 6, lane = tid & 63;
  const int wr = wave >> 2, wc = wave & 3;   // 2 x 4 wave grid
  const int lrow = lane & 15;
  const int lk8  = (lane >> 4) * 8;

  f32x4 acc[4][2];
#pragma unroll
  for (int m = 0; m < 4; ++m)
#pragma unroll
    for (int n = 0; n < 2; ++n) acc[m][n] = (f32x4){0.f, 0.f, 0.f, 0.f};

  float4 ra[4], rw[4];
  s16x8 rab[2];
#define LOAD_TILE(KT)                                                          \
  {                                                                            \
    const int kb = (KT) * 64;                                                  \
    if (ab) {                                                                  \
      _Pragma("unroll") for (int i = 0; i < 2; ++i) {                          \
        const int idx = tid + i * 512;                                         \
        const int r = idx >> 3, c8 = (idx & 7) * 8;                            \
        rab[i] = *(const s16x8*)(Ah + (long)(brow + r) * 1024 + kb + c8);      \
      }                                                                        \
    } else {                                                                   \
      _Pragma("unroll") for (int i = 0; i < 4; ++i) {                          \
        const int idx = tid + i * 512;                                         \
        const int r = idx >> 4, c4 = (idx & 15) * 4;                           \
        ra[i] = *(const float4*)(Af + (long)(brow + r) * 1024 + kb + c4);      \
      }                                                                        \
    }                                                                          \
    _Pragma("unroll") for (int i = 0; i < 4; ++i) {                            \
      const int idx = tid + i * 512;                                           \
      const int r = idx >> 4, c4 = (idx & 15) * 4;                             \
      rw[i] = *(const float4*)(W + (long)(bcol + r) * wstr + kb + c4);         \
    }                                                                          \
  }
#define WRITE_TILE()                                                           \
  {                                                                            \
    if (ab) {                                                                  \
      _Pragma("unroll") for (int i = 0; i < 2; ++i) {                          \
        const int idx = tid + i * 512;                                         \
        const int r = idx >> 3, c8 = (idx & 7) * 8;                            \
        *(s16x8*)(&(*As)[r][c8]) = rab[i];                                     \
      }                                                                        \
    } else {                                                                   \
      _Pragma("unroll") for (int i = 0; i < 4; ++i) {                          \
        const int idx = tid + i * 512;                                         \
        const int r = idx >> 4, c4 = (idx & 15) * 4;                           \
        *(short4*)(&(*As)[r][c4]) =                                            \
            short4{f2bf(ra[i].x), f2bf(ra[i].y), f2bf(ra[i].z), f2bf(ra[i].w)};\
      }                                                                        \
    }                                                                          \
    _Pragma("unroll") for (int i = 0; i < 4; ++i) {                            \
      const int idx = tid + i * 512;                                           \
      const int r = idx >> 4, c4 = (idx & 15) * 4;                             \
      *(short4*)(&(*Bs)[r][c4]) =                                              \
          short4{f2bf(rw[i].x), f2bf(rw[i].y), f2bf(rw[i].z), f2bf(rw[i].w)};  \
    }                                                                          \
  }

  const int ntiles = ga.klen[z] / 64;
  LOAD_TILE(0);
  WRITE_TILE();
  __syncthreads();
  for (int kt = 0; kt < ntiles; ++kt) {
    const bool more = (kt + 1 < ntiles);
    if (more) LOAD_TILE(kt + 1);  // reg-staged; in flight during MFMA phase
#pragma unroll
    for (int kk = 0; kk < 64; kk += 32) {
      s16x8 af[4], bf[2];
#pragma unroll
      for (int m = 0; m < 4; ++m)
        af[m] = *(const s16x8*)(&(*As)[wr * 64 + m * 16 + lrow][kk + lk8]);
#pragma unroll
      for (int n = 0; n < 2; ++n)
        bf[n] = *(const s16x8*)(&(*Bs)[wc * 32 + n * 16 + lrow][kk + lk8]);
#pragma unroll
      for (int m = 0; m < 4; ++m)
#pragma unroll
        for (int n = 0; n < 2; ++n)
          acc[m][n] = __builtin_amdgcn_mfma_f32_16x16x32_bf16(
              af[m], bf[n], acc[m][n], 0, 0, 0);
    }
    if (more) {
      __syncthreads();   // all waves done reading the buffer
      WRITE_TILE();
      __syncthreads();   // buffer ready for next MFMA phase
    }
  }
#undef LOAD_TILE
#undef WRITE_TILE

  // C/D layout: col=lane&15, row=(lane>>4)*4+reg; bf16 partial store
#pragma unroll
  for (int m = 0; m < 4; ++m) {
#pragma unroll
    for (int n = 0; n < 2; ++n) {
      const int col = bcol + wc * 32 + n * 16 + lrow;
#pragma unroll
      for (int r = 0; r < 4; ++r) {
        const int row = brow + wr * 64 + m * 16 + (lane >> 4) * 4 + r;
        out[(long)row * N + col] = f2bf(acc[m][n][r]);
      }
    }
  }
}

// ---------------------------------------------------------------------------
// f32 -> bf16 converter (grid-stride over nb blocks of 512 threads).
// ---------------------------------------------------------------------------
__device__ __forceinline__ void conv_b(const float* __restrict__ src,
                                       __hip_bfloat16* __restrict__ dst,
                                       long nelem, int bid, int nb) {
  const long total = nelem >> 2;
  for (long i = (long)bid * 512 + threadIdx.x; i < total; i += (long)nb * 512) {
    f32x4 v = LD4(src + i * 4);
    *(short4*)((short*)dst + i * 4) =
        short4{f2bf(v[0]), f2bf(v[1]), f2bf(v[2]), f2bf(v[3])};
  }
}

// ---------------------------------------------------------------------------
// fusedA: conv (blocks 0..255) || GEMM (256..895): 20 slots =
// 16 att-gate (f32 A) + 4 sh1@lWhh lbase-part (to gpLB slots 0-3).
// ---------------------------------------------------------------------------
__global__ __launch_bounds__(512, 4) void fusedA(
    GemmArgs ga, short* __restrict__ gps,
    const float* __restrict__ vkey, const float* __restrict__ lkey,
    const float* __restrict__ vval, const float* __restrict__ lval,
    __hip_bfloat16* __restrict__ vkb, __hip_bfloat16* __restrict__ lkb,
    __hip_bfloat16* __restrict__ vvb, __hip_bfloat16* __restrict__ lvb) {
  __shared__ __align__(16) union { struct { ldsT As; ldsT Bs; } g; } sm;
  const int bid = blockIdx.x;
  if (bid < 256) {
    conv_b(vkey, vkb, (long)B * NV * 1024, bid, 256);
    conv_b(lkey, lkb, (long)B * NL * 1024, bid, 256);
    conv_b(vval, vvb, (long)B * NV * 1024, bid, 256);
    conv_b(lval, lvb, (long)B * NL * 1024, bid, 256);
  } else {
    const int g = bid - 256;                  // 0..639
    gemm_body(ga, 4096, gps, g & 31, 0, g >> 5, &sm.g.As, &sm.g.Bs);
  }
}

// ---------------------------------------------------------------------------
// att LSTM cell: gates = sum of 16 bf16 partial slots + biases -> h_att
// (f32 + bf16), new_h[0]/new_c[0] to d_out.
// ---------------------------------------------------------------------------
__global__ __launch_bounds__(256) void lstm_att(
    const short* __restrict__ gps, const float* __restrict__ bih,
    const float* __restrict__ bhh, const float* __restrict__ c_prev,
    float* __restrict__ h, __hip_bfloat16* __restrict__ hb,
    float* __restrict__ out) {
  long idx = ((long)blockIdx.x * 256 + threadIdx.x) * 4;
  if (idx >= BD) return;
  int b = (int)(idx >> 10), d = (int)(idx & 1023);
  const long base = (long)b * 4096 + d;
  f32x4 g[4];
#pragma unroll
  for (int gi = 0; gi < 4; ++gi) {
    const long o = base + gi * 1024;
    f32x4 v = LD4(bih + gi * 1024 + d) + LD4(bhh + gi * 1024 + d);
#pragma unroll
    for (int s = 0; s < 16; ++s) v += ld4bf(gps + SGPA + s * SLs + o);
    g[gi] = v;
  }
  f32x4 cp = LD4(c_prev + idx), cc, hh;
#pragma unroll
  for (int j = 0; j < 4; ++j) {
    float ccj = sigf(g[1][j]) * cp[j] + sigf(g[0][j]) * tanhf(g[2][j]);
    cc[j] = ccj;
    hh[j] = sigf(g[3][j]) * tanhf(ccj);
  }
  ST4(h + idx, hh);
  *(short4*)((short*)hb + idx) =
      short4{f2bf(hh[0]), f2bf(hh[1]), f2bf(hh[2]), f2bf(hh[3])};
  ST4(out + O4 + idx, hh);   // new_h[0] == hA/accum == h_att
  ST4(out + O5 + idx, cc);   // new_c[0] == cA/accum == c_att
}

// ---------------------------------------------------------------------------
// attn_mega (proven form): 4 attention steps per b, 1024 threads;
// keys staged into LDS from bf16 cache; bf16 values, ILP ctx; kvs in regs;
// softmax over ORIGINAL keys (slot-uniform update cancels).
// ---------------------------------------------------------------------------
__global__ __launch_bounds__(1024) void attn_mega(
    const float* __restrict__ h_att, const float* __restrict__ kv0,
    const __hip_bfloat16* __restrict__ vkb, const __hip_bfloat16* __restrict__ lkb,
    const __hip_bfloat16* __restrict__ vvb, const __hip_bfloat16* __restrict__ lvb,
    __hip_bfloat16* __restrict__ vctxB, __hip_bfloat16* __restrict__ lctxB,
    float* __restrict__ out_kvs) {
  const int b = blockIdx.x, tid = threadIdx.x;   // tid = d column
  __shared__ short K[56][1024];                  // 112 KB bf16 keys
  __shared__ float q[1024];
  __shared__ float wgt[64];
  const int wave = tid >> 6, lane = tid & 63;

  for (int i = tid; i < 56 * 128; i += 1024) {
    const int r = i >> 7, c8 = (i & 127) * 8;
    const __hip_bfloat16* kp = (r < NV)
        ? vkb + ((long)b * NV + r) * 1024
        : lkb + ((long)b * NL + (r - NV)) * 1024;
    *(s16x8*)(&K[r][c8]) = *(const s16x8*)(kp + c8);
  }

  const float ha = h_att[(long)b * 1024 + tid];
  float kv = kv0[(long)b * 1024 + tid];

  for (int step = 0; step < 4; ++step) {
    q[tid] = ha + kv;
    __syncthreads();
    for (int n = wave; n < NV + NL; n += 16) {
      float s = 0.f;
#pragma unroll
      for (int j = 0; j < 2; ++j) {
        const int base = lane * 8 + j * 512;
        s16x8 k8 = *(const s16x8*)(&K[n][base]);
        f32x4 q0 = *(const f32x4*)(&q[base]);
        f32x4 q1 = *(const f32x4*)(&q[base + 4]);
#pragma unroll
        for (int e = 0; e < 4; ++e) {
          s += bf2f(k8[e]) * q0[e];
          s += bf2f(k8[e + 4]) * q1[e];
        }
      }
      for (int m = 32; m >= 1; m >>= 1) s += __shfl_xor(s, m);
      if (lane == 0) wgt[n] = s * (1.0f / 32.0f);
    }
    __syncthreads();
    if (wave == 0) {
      float x = (lane < NV) ? wgt[lane] : -1e30f;
      float m = x;
      for (int k = 32; k >= 1; k >>= 1) m = fmaxf(m, __shfl_xor(m, k));
      float e = (lane < NV) ? expf(x - m) : 0.f;
      float ssum = e;
      for (int k = 32; k >= 1; k >>= 1) ssum += __shfl_xor(ssum, k);
      if (lane < NV) wgt[lane] = e / ssum;
    } else if (wave == 1) {
      float x = (lane < NL) ? wgt[NV + lane] : -1e30f;
      float m = x;
      for (int k = 32; k >= 1; k >>= 1) m = fmaxf(m, __shfl_xor(m, k));
      float e = (lane < NL) ? expf(x - m) : 0.f;
      float ssum = e;
      for (int k = 32; k >= 1; k >>= 1) ssum += __shfl_xor(ssum, k);
      if (lane < NL) wgt[NV + lane] = e / ssum;
    }
    __syncthreads();
    const __hip_bfloat16* vb = vvb + (long)b * NV * 1024 + tid;
    float a0 = 0.f, a1 = 0.f, a2 = 0.f, a3 = 0.f;
#pragma unroll
    for (int n = 0; n < NV; n += 4) {
      a0 += __bfloat162float(vb[(long)(n + 0) * 1024]) * wgt[n + 0];
      a1 += __bfloat162float(vb[(long)(n + 1) * 1024]) * wgt[n + 1];
      a2 += __bfloat162float(vb[(long)(n + 2) * 1024]) * wgt[n + 2];
      a3 += __bfloat162float(vb[(long)(n + 3) * 1024]) * wgt[n + 3];
    }
    const float vc = (a0 + a1) + (a2 + a3);
    const __hip_bfloat16* lb = lvb + (long)b * NL * 1024 + tid;
    float c0 = 0.f, c1 = 0.f, c2 = 0.f, c3 = 0.f;
#pragma unroll
    for (int n = 0; n < NL; n += 4) {
      c0 += __bfloat162float(lb[(long)(n + 0) * 1024]) * wgt[NV + n + 0];
      c1 += __bfloat162float(lb[(long)(n + 1) * 1024]) * wgt[NV + n + 1];
      c2 += __bfloat162float(lb[(long)(n + 2) * 1024]) * wgt[NV + n + 2];
      c3 += __bfloat162float(lb[(long)(n + 3) * 1024]) * wgt[NV + n + 3];
    }
    const float lc = (c0 + c1) + (c2 + c3);
    const long orow = ((long)step * 128 + b) * 1024 + tid;
    vctxB[orow] = __float2bfloat16(vc);
    lctxB[orow] = __float2bfloat16(lc);
    kv = tanhf(kv + vc + lc);
    __syncthreads();
  }
  out_kvs[(long)b * 1024 + tid] = kv;
}

// ---------------------------------------------------------------------------
// fusedD: batched lang-gates GEMM (blocks 0..511, slots 0-3) ||
//         h_att lbase-part GEMM (blocks 512..639, slots 4-7). Independent.
// ---------------------------------------------------------------------------
__global__ __launch_bounds__(512, 4) void fusedD(GemmArgs ga,
                                                 short* __restrict__ gps) {
  __shared__ __align__(16) union { struct { ldsT As; ldsT Bs; } g; } sm;
  const int bid = blockIdx.x;
  if (bid < 512) {
    gemm_body(ga, 4096, gps, bid & 31, (bid >> 5) & 3, bid >> 7,
              &sm.g.As, &sm.g.Bs);
  } else {
    const int h = bid - 512;                  // 0..127
    gemm_body(ga, 4096, gps, h & 31, 0, 4 + (h >> 5), &sm.g.As, &sm.g.Bs);
  }
}

// ---------------------------------------------------------------------------
// batched lang LSTM (M=512): gates = 4 gpB slots[row] + 8 gpLB slots[b]
// (all bf16) + lbih + lbhh; c_prev = sc1[b].
// ---------------------------------------------------------------------------
__global__ __launch_bounds__(256) void lstm_batch(
    const short* __restrict__ gps, const float* __restrict__ lbih,
    const float* __restrict__ lbhh, const float* __restrict__ sc1,
    float* __restrict__ hB, float* __restrict__ cB) {
  long idx = ((long)blockIdx.x * 256 + threadIdx.x) * 4;
  if (idx >= 512L * 1024) return;
  const int row = (int)(idx >> 10);   // step*128+b
  const int b = row & 127;
  const int d = (int)(idx & 1023);
  const long base = (long)row * 4096 + d;
  const long bbase = (long)b * 4096 + d;
  f32x4 g[4];
#pragma unroll
  for (int gi = 0; gi < 4; ++gi) {
    const long o = gi * 1024;
    f32x4 v = LD4(lbih + gi * 1024 + d) + LD4(lbhh + gi * 1024 + d);
#pragma unroll
    for (int s = 0; s < 4; ++s) v += ld4bf(gps + SGPB + s * SLBs + base + o);
#pragma unroll
    for (int s = 0; s < 8; ++s) v += ld4bf(gps + SGPLB + s * SLs + bbase + o);
    g[gi] = v;
  }
  f32x4 cp = LD4(sc1 + (long)b * 1024 + d), cc, hh;
#pragma unroll
  for (int j = 0; j < 4; ++j) {
    float ccj = sigf(g[1][j]) * cp[j] + sigf(g[0][j]) * tanhf(g[2][j]);
    cc[j] = ccj;
    hh[j] = sigf(g[3][j]) * tanhf(ccj);
  }
  ST4(cB + idx, cc);
  ST4(hB + idx, hh);
}

// ---------------------------------------------------------------------------
// fusedC: conf GEMM (blocks 0..127, slots 0-3) || key-output finalize
// (128..1919): stages S[b][d] = sum_steps hB in LDS, out = key + 0.01*S.
// ---------------------------------------------------------------------------
__global__ __launch_bounds__(512, 4) void fusedC(
    GemmArgs ga, short* __restrict__ gps, const float* __restrict__ hB,
    const __hip_bfloat16* __restrict__ vkb, const __hip_bfloat16* __restrict__ lkb,
    float* __restrict__ out) {
  __shared__ __align__(16) union {
    struct { ldsT As; ldsT Bs; } g;
    struct { float Ssh[1024]; } f;
  } sm;
  const int bid = blockIdx.x;
  if (bid < 128) {
    gemm_body(ga, 1024, gps, bid & 7, (bid >> 3) & 3, bid >> 5,
              &sm.g.As, &sm.g.Bs);
    return;
  }
  const int fb = bid - 128;                 // 0..1791
  const long base = (long)fb * 4096;
  const bool isV = (base < VK);
  const int b = isV ? (int)(base / (NV * 1024))
                    : (int)((base - VK) / (NL * 1024));
  const int tid = threadIdx.x;
  for (int d = tid; d < 1024; d += 512) {
    float s = 0.f;
#pragma unroll
    for (int st = 0; st < 4; ++st) s += hB[((long)st * 128 + b) * 1024 + d];
    sm.f.Ssh[d] = s;
  }
  __syncthreads();
  const long idx = base + (long)tid * 8;
  const int d = (int)(idx & 1023);
  if (isV) {
    s16x8 k8 = *(const s16x8*)((const short*)vkb + idx);
    f32x4 o0, o1;
#pragma unroll
    for (int j = 0; j < 4; ++j) {
      o0[j] = bf2f(k8[j]) + 0.01f * sm.f.Ssh[d + j];
      o1[j] = bf2f(k8[j + 4]) + 0.01f * sm.f.Ssh[d + 4 + j];
    }
    ST4(out + O1 + idx, o0);
    ST4(out + O1 + idx + 4, o1);
  } else {
    const long r = idx - VK;
    s16x8 k8 = *(const s16x8*)((const short*)lkb + r);
    f32x4 o0, o1;
#pragma unroll
    for (int j = 0; j < 4; ++j) {
      o0[j] = bf2f(k8[j]) + 0.01f * sm.f.Ssh[d + j];
      o1[j] = bf2f(k8[j + 4]) + 0.01f * sm.f.Ssh[d + 4 + j];
    }
    ST4(out + O2 + r, o0);
    ST4(out + O2 + r + 4, o1);
  }
}

// ---------------------------------------------------------------------------
// halt_scan: per-b halting recurrence over 4 steps (sums 4 bf16 conf slots).
// ---------------------------------------------------------------------------
__global__ __launch_bounds__(256) void halt_scan(
    const short* __restrict__ gps, const float* __restrict__ cb1,
    const float* __restrict__ W2, const float* __restrict__ b2,
    const float* __restrict__ hB, const float* __restrict__ cB,
    const int* __restrict__ it, float* __restrict__ out) {
  const int b = blockIdx.x, tid = threadIdx.x;
  const int d0 = tid * 4;
  __shared__ float red[256];
  __shared__ float p_sh;
  const f32x4 w4 = LD4(W2 + d0);
  const f32x4 cb = LD4(cb1 + d0);
  f32x4 hl_acc = (f32x4){0.f, 0.f, 0.f, 0.f}, cl_acc = hl_acc;
  float a = 0.f, sel = 1.f, cost = 0.f;

  for (int i = 0; i < 4; ++i) {
    const long o = ((long)i * 128 + b) * 1024 + d0;
    f32x4 rv = cb;
#pragma unroll
    for (int s = 0; s < 4; ++s) rv += ld4bf(gps + SGPC + s * SLCs + o);
    float part = 0.f;
#pragma unroll
    for (int j = 0; j < 4; ++j) part += fmaxf(rv[j], 0.f) * w4[j];
    red[tid] = part;
    __syncthreads();
    for (int s = 128; s > 0; s >>= 1) {
      if (tid < s) red[tid] += red[tid + s];
      __syncthreads();
    }
    if (tid == 0) p_sh = sigf(red[0] + b2[0]);
    __syncthreads();
    const float p = p_sh;
    const float bs = p * (1.f - a) * sel;
    f32x4 hl = LD4(hB + o), cl = LD4(cB + o);
    hl_acc += hl * bs;
    cl_acc += cl * bs;
    cost += (float)(i + 1) * (1.f - p) * sel;
    a += bs;
    sel = (a < 1.f - EPS) ? sel : 0.f;
    __syncthreads();
  }
  const float inv_a = 1.f / a;
  const long ob = (long)b * 1024 + d0;
  ST4(out + ob, hl_acc * inv_a);             // outA
  ST4(out + O4 + BD + ob, hl_acc * inv_a);   // new_h[1]
  ST4(out + O5 + BD + ob, cl_acc * inv_a);   // new_c[1]
  if (tid == 0) out[O3 + b] = cost * ((it[b] > 0) ? 1.f : 0.f);
}

// ---------------------------------------------------------------------------
extern "C" void kernel_launch(void* const* d_in, const int* in_sizes, int n_in,
                              void* d_out, int out_size, void* d_ws, size_t ws_size,
                              hipStream_t stream) {
  const float* xt   = (const float*)d_in[0];
  const int*   it   = (const int*)d_in[1];
  const float* fc   = (const float*)d_in[2];
  const float* vval = (const float*)d_in[3];
  const float* vkey = (const float*)d_in[4];
  const float* lval = (const float*)d_in[5];
  const float* lkey = (const float*)d_in[6];
  const float* kv0  = (const float*)d_in[7];
  const float* sh   = (const float*)d_in[8];   // [2,B,D]
  const float* sc   = (const float*)d_in[9];   // [2,B,D]
  // d_in[10] = max_att_step (4)
  const float* aWih = (const float*)d_in[11];  // [4096,3072]
  const float* aWhh = (const float*)d_in[12];  // [4096,1024]
  const float* abih = (const float*)d_in[13];
  const float* abhh = (const float*)d_in[14];
  const float* lWih = (const float*)d_in[15];  // [4096,3072]
  const float* lWhh = (const float*)d_in[16];  // [4096,1024]
  const float* lbih = (const float*)d_in[17];
  const float* lbhh = (const float*)d_in[18];
  const float* cW1  = (const float*)d_in[19];  // [1024,1024]
  const float* cb1  = (const float*)d_in[20];
  const float* cW2  = (const float*)d_in[21];  // [1,1024]
  const float* cb2  = (const float*)d_in[22];

  float* ws = (float*)d_ws;
  short* gps = (short*)d_ws;
  float* h_att = ws + OFF_HATT;
  float* hB    = ws + OFF_HLB;
  float* cB    = ws + OFF_CLB;
  __hip_bfloat16* vvb  = (__hip_bfloat16*)(ws + OFF_VVB);
  __hip_bfloat16* lvb  = (__hip_bfloat16*)(ws + OFF_LVB);
  __hip_bfloat16* vkb  = (__hip_bfloat16*)(ws + OFF_VKB);
  __hip_bfloat16* lkb  = (__hip_bfloat16*)(ws + OFF_LKB);
  __hip_bfloat16* hatb = (__hip_bfloat16*)(ws + OFF_HATB);
  __hip_bfloat16* vcxb = (__hip_bfloat16*)(ws + OFF_VCXB);
  __hip_bfloat16* lcxb = (__hip_bfloat16*)(ws + OFF_LCXB);

  const float* sh1 = sh + BD;  // state_h[1]
  const float* sc0 = sc;       // state_c[0]
  const float* sc1 = sc + BD;  // state_c[1]
  float* out = (float*)d_out;

  // 1) fusedA: conv (256 blocks) || 20-slot GEMM (att gates + sh1-lbase part)
  {
    GemmArgs ga = {};
    const float* Aops[4] = {sh1, fc, xt, sh};
    const float* Wops[4] = {aWih, aWih + 1024, aWih + 2048, aWhh};
    const long wstrs[4] = {3072, 3072, 3072, 1024};
    for (int p = 0; p < 4; ++p)
      for (int q = 0; q < 4; ++q) {
        const int s = p * 4 + q;
        ga.A[s] = Aops[p] + q * 256;
        ga.W[s] = Wops[p] + q * 256;
        ga.wstride[s] = wstrs[p];
        ga.ooff[s] = SGPA + (long)s * SLs;
        ga.klen[s] = 256;
      }
    for (int q = 0; q < 4; ++q) {           // sh1 @ lWhh quarters -> gpLB 0-3
      const int s = 16 + q;
      ga.A[s] = sh1 + q * 256;
      ga.W[s] = lWhh + q * 256;
      ga.wstride[s] = 1024;
      ga.ooff[s] = SGPLB + (long)q * SLs;
      ga.klen[s] = 256;
    }
    fusedA<<<896, 512, 0, stream>>>(ga, gps, vkey, lkey, vval, lval,
                                    vkb, lkb, vvb, lvb);
  }
  // 2) att LSTM -> h_att f32+bf16 (+ new_h[0]/new_c[0] to out)
  lstm_att<<<128, 256, 0, stream>>>(gps, abih, abhh, sc0, h_att, hatb, out);

  // 3) attention (proven 1024-thread LDS-key form)
  attn_mega<<<128, 1024, 0, stream>>>(h_att, kv0, vkb, lkb, vvb, lvb,
                                      vcxb, lcxb, out + O6);

  // 4) fusedD: batched gates GEMM (slots 0-3) || h_att lbase GEMM (slots 4-7)
  {
    GemmArgs ga = {};
    ga.A[0] = vcxb;                                    ga.W[0] = lWih;
    ga.wstride[0] = 3072; ga.abf16[0] = 1;
    ga.ooff[0] = SGPB;             ga.klen[0] = 512;
    ga.A[1] = (const void*)((const short*)vcxb + 512); ga.W[1] = lWih + 512;
    ga.wstride[1] = 3072; ga.abf16[1] = 1;
    ga.ooff[1] = SGPB + SLBs;      ga.klen[1] = 512;
    ga.A[2] = lcxb;                                    ga.W[2] = lWih + 1024;
    ga.wstride[2] = 3072; ga.abf16[2] = 1;
    ga.ooff[2] = SGPB + 2 * SLBs;  ga.klen[2] = 512;
    ga.A[3] = (const void*)((const short*)lcxb + 512); ga.W[3] = lWih + 1536;
    ga.wstride[3] = 3072; ga.abf16[3] = 1;
    ga.ooff[3] = SGPB + 3 * SLBs;  ga.klen[3] = 512;
    for (int q = 0; q < 4; ++q) {           // hatb @ lWih[:,2048:] quarters
      const int s = 4 + q;
      ga.A[s] = (const void*)((const short*)hatb + q * 256);
      ga.W[s] = lWih + 2048 + q * 256;
      ga.wstride[s] = 3072;
      ga.abf16[s] = 1;
      ga.ooff[s] = SGPLB + (long)(4 + q) * SLs;
      ga.klen[s] = 256;
    }
    fusedD<<<640, 512, 0, stream>>>(ga, gps);
  }
  // 5) batched lang LSTM (4 gpB slots + 8 gpLB slots + biases)
  lstm_batch<<<512, 256, 0, stream>>>(gps, lbih, lbhh, sc1, hB, cB);

  // 6) fusedC: conf GEMM (128) || key-output finalize (1792)
  {
    GemmArgs ga = {};
    for (int q = 0; q < 4; ++q) {
      ga.A[q] = hB + q * 256;
      ga.W[q] = cW1 + q * 256;
      ga.wstride[q] = 1024;
      ga.ooff[q] = SGPC + (long)q * SLCs;
      ga.klen[q] = 256;
    }
    fusedC<<<1920, 512, 0, stream>>>(ga, gps, hB, vkb, lkb, out);
  }
  // 7) halting scan -> outA, new_h[1], new_c[1], cost
  halt_scan<<<128, 256, 0, stream>>>(gps, cb1, cW2, cb2, hB, cB, it, out);
}

// Round 23
// 132.091 us; speedup vs baseline: 1.5920x; 1.0073x over previous
//
#include <hip/hip_runtime.h>
#include <hip/hip_bf16.h>

// Sizes (fixed by the reference setup)
constexpr int B  = 128;
constexpr int D  = 1024;
constexpr int NV = 36;
constexpr int NL = 20;
constexpr int BD = B * D;              // 131072
constexpr float EPS = 0.01f;
constexpr int NSLOT = 20;

// bf16 partial-slot offsets (in SHORT elements from ws base)
constexpr long SLs  = 524288;                 // [128][4096] bf16 slot
constexpr long SLBs = 2097152;                // [512][4096] bf16 slot
constexpr long SLCs = 524288;                 // [512][1024] bf16 slot
constexpr long SGPA  = 0;                     // 16 att-gate slots
constexpr long SGPLB = SGPA + 16 * SLs;       // 8 lbase slots
constexpr long SGPB  = SGPLB + 8 * SLs;       // 4 lang-gate slots
constexpr long SGPC  = SGPB + 4 * SLBs;       // 4 conf slots

// float offsets (from ws base, after the partial region)
constexpr long FBASE     = (SGPC + 4 * SLCs) / 2;   // floats
constexpr long OFF_HATT  = FBASE;                   // h_att f32 [128][1024]
constexpr long OFF_HLB   = OFF_HATT + BD;           // hB [512][1024]
constexpr long OFF_CLB   = OFF_HLB + 524288;        // cB
constexpr long OFF_VVB   = OFF_CLB + 524288;        // bf16 vval cache
constexpr long OFF_LVB   = OFF_VVB + 2359296;
constexpr long OFF_VKB   = OFF_LVB + 1310720;
constexpr long OFF_LKB   = OFF_VKB + 2359296;
constexpr long OFF_HATB  = OFF_LKB + 1310720;       // bf16 h_att
constexpr long OFF_VCXB  = OFF_HATB + 65536;        // bf16 vctx [512][1024]
constexpr long OFF_LCXB  = OFF_VCXB + 262144;       // bf16 lctx

typedef float f32x4 __attribute__((ext_vector_type(4)));
typedef short s16x8 __attribute__((ext_vector_type(8)));
typedef short ldsT[128][72];

__device__ __forceinline__ float sigf(float x) { return 1.f / (1.f + expf(-x)); }

__device__ __forceinline__ short f2bf(float f) {
  __hip_bfloat16 h = __float2bfloat16(f);
  return *reinterpret_cast<short*>(&h);
}
__device__ __forceinline__ float bf2f(short s) {
  unsigned u = ((unsigned)(unsigned short)s) << 16;
  return __uint_as_float(u);
}
__device__ __forceinline__ f32x4 LD4(const float* p) { return *(const f32x4*)p; }
__device__ __forceinline__ void ST4(float* p, f32x4 v) { *(f32x4*)p = v; }
__device__ __forceinline__ f32x4 ld4bf(const short* p) {
  short4 s = *(const short4*)p;
  return (f32x4){bf2f(s.x), bf2f(s.y), bf2f(s.z), bf2f(s.w)};
}

// d_out section offsets
constexpr long O1 = BD;
constexpr long O2 = O1 + (long)B * NV * D;
constexpr long O3 = O2 + (long)B * NL * D;
constexpr long O4 = O3 + B;
constexpr long O5 = O4 + 2L * BD;
constexpr long O6 = O5 + 2L * BD;
constexpr long O7 = O6 + BD;
constexpr long VK = (long)B * NV * D;
constexpr long LK = (long)B * NL * D;

// ---------------------------------------------------------------------------
// GEMM body (round-18 proven form, templated on BN): tile BM=128 BN=BNT
// BK=64, 512 threads = 8 waves, single-buffered LDS, 1-deep reg prefetch.
// BNT=128: 2x4 wave grid, wave 64x32 out, acc[4][2] (bit-identical to r18).
// BNT=64 : 4x2 wave grid, wave 32x32 out, acc[2][2] (halved W staging; more
//          blocks for the latency-bound weight stream).
// Writes bf16 partials. A may be f32 or bf16. Per-slot klen.
// ---------------------------------------------------------------------------
struct GemmArgs {
  const void* A[NSLOT];    // row stride 1024 elements
  const float* W[NSLOT];   // row stride wstride
  long wstride[NSLOT];
  long ooff[NSLOT];        // output offset in SHORT elements
  int abf16[NSLOT];
  int klen[NSLOT];         // K per slot (multiple of 64)
};

template <int BNT>
__device__ __forceinline__ void gemm_body(const GemmArgs& ga, int N,
                                          short* __restrict__ gps,
                                          int bx, int by, int bz,
                                          ldsT* As, ldsT* Bs) {
  constexpr int WCN = BNT / 32;        // wave cols: 4 (BN=128) or 2 (BN=64)
  constexpr int WRN = 8 / WCN;         // wave rows: 2 or 4
  constexpr int MR  = 128 / WRN / 16;  // acc row frags: 4 or 2
  constexpr int WIT = BNT / 32;        // W float4 stage iters: 4 or 2

  const int z = bz;
  const int ab = ga.abf16[z];
  const float* __restrict__ Af = (const float*)ga.A[z];
  const short* __restrict__ Ah = (const short*)ga.A[z];
  const float* __restrict__ W = ga.W[z];
  const long wstr = ga.wstride[z];
  const int brow = by * 128;
  const int bcol = bx * BNT;
  short* __restrict__ out = gps + ga.ooff[z];

  const int tid = threadIdx.x;
  const int wave = tid >> 6, lane = tid & 63;
  const int wr = wave / WCN, wc = wave % WCN;
  const int lrow = lane & 15;
  const int lk8  = (lane >> 4) * 8;

  f32x4 acc[MR][2];
#pragma unroll
  for (int m = 0; m < MR; ++m)
#pragma unroll
    for (int n = 0; n < 2; ++n) acc[m][n] = (f32x4){0.f, 0.f, 0.f, 0.f};

  float4 ra[4], rw[WIT];
  s16x8 rab[2];
#define LOAD_TILE(KT)                                                          \
  {                                                                            \
    const int kb = (KT) * 64;                                                  \
    if (ab) {                                                                  \
      _Pragma("unroll") for (int i = 0; i < 2; ++i) {                          \
        const int idx = tid + i * 512;                                         \
        const int r = idx >> 3, c8 = (idx & 7) * 8;                            \
        rab[i] = *(const s16x8*)(Ah + (long)(brow + r) * 1024 + kb + c8);      \
      }                                                                        \
    } else {                                                                   \
      _Pragma("unroll") for (int i = 0; i < 4; ++i) {                          \
        const int idx = tid + i * 512;                                         \
        const int r = idx >> 4, c4 = (idx & 15) * 4;                           \
        ra[i] = *(const float4*)(Af + (long)(brow + r) * 1024 + kb + c4);      \
      }                                                                        \
    }                                                                          \
    _Pragma("unroll") for (int i = 0; i < WIT; ++i) {                          \
      const int idx = tid + i * 512;                                           \
      const int r = idx >> 4, c4 = (idx & 15) * 4;                             \
      rw[i] = *(const float4*)(W + (long)(bcol + r) * wstr + kb + c4);         \
    }                                                                          \
  }
#define WRITE_TILE()                                                           \
  {                                                                            \
    if (ab) {                                                                  \
      _Pragma("unroll") for (int i = 0; i < 2; ++i) {                          \
        const int idx = tid + i * 512;                                         \
        const int r = idx >> 3, c8 = (idx & 7) * 8;                            \
        *(s16x8*)(&(*As)[r][c8]) = rab[i];                                     \
      }                                                                        \
    } else {                                                                   \
      _Pragma("unroll") for (int i = 0; i < 4; ++i) {                          \
        const int idx = tid + i * 512;                                         \
        const int r = idx >> 4, c4 = (idx & 15) * 4;                           \
        *(short4*)(&(*As)[r][c4]) =                                            \
            short4{f2bf(ra[i].x), f2bf(ra[i].y), f2bf(ra[i].z), f2bf(ra[i].w)};\
      }                                                                        \
    }                                                                          \
    _Pragma("unroll") for (int i = 0; i < WIT; ++i) {                          \
      const int idx = tid + i * 512;                                           \
      const int r = idx >> 4, c4 = (idx & 15) * 4;                             \
      *(short4*)(&(*Bs)[r][c4]) =                                              \
          short4{f2bf(rw[i].x), f2bf(rw[i].y), f2bf(rw[i].z), f2bf(rw[i].w)};  \
    }                                                                          \
  }

  const int ntiles = ga.klen[z] / 64;
  LOAD_TILE(0);
  WRITE_TILE();
  __syncthreads();
  for (int kt = 0; kt < ntiles; ++kt) {
    const bool more = (kt + 1 < ntiles);
    if (more) LOAD_TILE(kt + 1);  // reg-staged; in flight during MFMA phase
#pragma unroll
    for (int kk = 0; kk < 64; kk += 32) {
      s16x8 af[MR], bf[2];
#pragma unroll
      for (int m = 0; m < MR; ++m)
        af[m] = *(const s16x8*)(&(*As)[wr * (MR * 16) + m * 16 + lrow][kk + lk8]);
#pragma unroll
      for (int n = 0; n < 2; ++n)
        bf[n] = *(const s16x8*)(&(*Bs)[wc * 32 + n * 16 + lrow][kk + lk8]);
#pragma unroll
      for (int m = 0; m < MR; ++m)
#pragma unroll
        for (int n = 0; n < 2; ++n)
          acc[m][n] = __builtin_amdgcn_mfma_f32_16x16x32_bf16(
              af[m], bf[n], acc[m][n], 0, 0, 0);
    }
    if (more) {
      __syncthreads();   // all waves done reading the buffer
      WRITE_TILE();
      __syncthreads();   // buffer ready for next MFMA phase
    }
  }
#undef LOAD_TILE
#undef WRITE_TILE

  // C/D layout: col=lane&15, row=(lane>>4)*4+reg; bf16 partial store
#pragma unroll
  for (int m = 0; m < MR; ++m) {
#pragma unroll
    for (int n = 0; n < 2; ++n) {
      const int col = bcol + wc * 32 + n * 16 + lrow;
#pragma unroll
      for (int r = 0; r < 4; ++r) {
        const int row = brow + wr * (MR * 16) + m * 16 + (lane >> 4) * 4 + r;
        out[(long)row * N + col] = f2bf(acc[m][n][r]);
      }
    }
  }
}

// ---------------------------------------------------------------------------
// f32 -> bf16 converter (grid-stride over nb blocks of 512 threads).
// ---------------------------------------------------------------------------
__device__ __forceinline__ void conv_b(const float* __restrict__ src,
                                       __hip_bfloat16* __restrict__ dst,
                                       long nelem, int bid, int nb) {
  const long total = nelem >> 2;
  for (long i = (long)bid * 512 + threadIdx.x; i < total; i += (long)nb * 512) {
    f32x4 v = LD4(src + i * 4);
    *(short4*)((short*)dst + i * 4) =
        short4{f2bf(v[0]), f2bf(v[1]), f2bf(v[2]), f2bf(v[3])};
  }
}

// ---------------------------------------------------------------------------
// fusedA: conv (blocks 0..255) || BN=64 GEMM (256..1535): 20 slots x 64
// N-tiles = 1280 blocks -> ~6 blocks/CU queue for the latency-bound
// weight stream (vs 3.5 at BN=128).
// ---------------------------------------------------------------------------
__global__ __launch_bounds__(512, 4) void fusedA(
    GemmArgs ga, short* __restrict__ gps,
    const float* __restrict__ vkey, const float* __restrict__ lkey,
    const float* __restrict__ vval, const float* __restrict__ lval,
    __hip_bfloat16* __restrict__ vkb, __hip_bfloat16* __restrict__ lkb,
    __hip_bfloat16* __restrict__ vvb, __hip_bfloat16* __restrict__ lvb) {
  __shared__ __align__(16) union { struct { ldsT As; ldsT Bs; } g; } sm;
  const int bid = blockIdx.x;
  if (bid < 256) {
    conv_b(vkey, vkb, (long)B * NV * 1024, bid, 256);
    conv_b(lkey, lkb, (long)B * NL * 1024, bid, 256);
    conv_b(vval, vvb, (long)B * NV * 1024, bid, 256);
    conv_b(lval, lvb, (long)B * NL * 1024, bid, 256);
  } else {
    const int g = bid - 256;                  // 0..1279
    gemm_body<64>(ga, 4096, gps, g & 63, 0, g >> 6, &sm.g.As, &sm.g.Bs);
  }
}

// ---------------------------------------------------------------------------
// att LSTM cell: gates = sum of 16 bf16 partial slots + biases -> h_att
// (f32 + bf16), new_h[0]/new_c[0] to d_out.
// ---------------------------------------------------------------------------
__global__ __launch_bounds__(256) void lstm_att(
    const short* __restrict__ gps, const float* __restrict__ bih,
    const float* __restrict__ bhh, const float* __restrict__ c_prev,
    float* __restrict__ h, __hip_bfloat16* __restrict__ hb,
    float* __restrict__ out) {
  long idx = ((long)blockIdx.x * 256 + threadIdx.x) * 4;
  if (idx >= BD) return;
  int b = (int)(idx >> 10), d = (int)(idx & 1023);
  const long base = (long)b * 4096 + d;
  f32x4 g[4];
#pragma unroll
  for (int gi = 0; gi < 4; ++gi) {
    const long o = base + gi * 1024;
    f32x4 v = LD4(bih + gi * 1024 + d) + LD4(bhh + gi * 1024 + d);
#pragma unroll
    for (int s = 0; s < 16; ++s) v += ld4bf(gps + SGPA + s * SLs + o);
    g[gi] = v;
  }
  f32x4 cp = LD4(c_prev + idx), cc, hh;
#pragma unroll
  for (int j = 0; j < 4; ++j) {
    float ccj = sigf(g[1][j]) * cp[j] + sigf(g[0][j]) * tanhf(g[2][j]);
    cc[j] = ccj;
    hh[j] = sigf(g[3][j]) * tanhf(ccj);
  }
  ST4(h + idx, hh);
  *(short4*)((short*)hb + idx) =
      short4{f2bf(hh[0]), f2bf(hh[1]), f2bf(hh[2]), f2bf(hh[3])};
  ST4(out + O4 + idx, hh);   // new_h[0] == hA/accum == h_att
  ST4(out + O5 + idx, cc);   // new_c[0] == cA/accum == c_att
}

// ---------------------------------------------------------------------------
// attn_mega (proven form): 4 attention steps per b, 1024 threads;
// keys staged into LDS from bf16 cache; bf16 values, ILP ctx; kvs in regs;
// softmax over ORIGINAL keys (slot-uniform update cancels).
// ---------------------------------------------------------------------------
__global__ __launch_bounds__(1024) void attn_mega(
    const float* __restrict__ h_att, const float* __restrict__ kv0,
    const __hip_bfloat16* __restrict__ vkb, const __hip_bfloat16* __restrict__ lkb,
    const __hip_bfloat16* __restrict__ vvb, const __hip_bfloat16* __restrict__ lvb,
    __hip_bfloat16* __restrict__ vctxB, __hip_bfloat16* __restrict__ lctxB,
    float* __restrict__ out_kvs) {
  const int b = blockIdx.x, tid = threadIdx.x;   // tid = d column
  __shared__ short K[56][1024];                  // 112 KB bf16 keys
  __shared__ float q[1024];
  __shared__ float wgt[64];
  const int wave = tid >> 6, lane = tid & 63;

  for (int i = tid; i < 56 * 128; i += 1024) {
    const int r = i >> 7, c8 = (i & 127) * 8;
    const __hip_bfloat16* kp = (r < NV)
        ? vkb + ((long)b * NV + r) * 1024
        : lkb + ((long)b * NL + (r - NV)) * 1024;
    *(s16x8*)(&K[r][c8]) = *(const s16x8*)(kp + c8);
  }

  const float ha = h_att[(long)b * 1024 + tid];
  float kv = kv0[(long)b * 1024 + tid];

  for (int step = 0; step < 4; ++step) {
    q[tid] = ha + kv;
    __syncthreads();
    for (int n = wave; n < NV + NL; n += 16) {
      float s = 0.f;
#pragma unroll
      for (int j = 0; j < 2; ++j) {
        const int base = lane * 8 + j * 512;
        s16x8 k8 = *(const s16x8*)(&K[n][base]);
        f32x4 q0 = *(const f32x4*)(&q[base]);
        f32x4 q1 = *(const f32x4*)(&q[base + 4]);
#pragma unroll
        for (int e = 0; e < 4; ++e) {
          s += bf2f(k8[e]) * q0[e];
          s += bf2f(k8[e + 4]) * q1[e];
        }
      }
      for (int m = 32; m >= 1; m >>= 1) s += __shfl_xor(s, m);
      if (lane == 0) wgt[n] = s * (1.0f / 32.0f);
    }
    __syncthreads();
    if (wave == 0) {
      float x = (lane < NV) ? wgt[lane] : -1e30f;
      float m = x;
      for (int k = 32; k >= 1; k >>= 1) m = fmaxf(m, __shfl_xor(m, k));
      float e = (lane < NV) ? expf(x - m) : 0.f;
      float ssum = e;
      for (int k = 32; k >= 1; k >>= 1) ssum += __shfl_xor(ssum, k);
      if (lane < NV) wgt[lane] = e / ssum;
    } else if (wave == 1) {
      float x = (lane < NL) ? wgt[NV + lane] : -1e30f;
      float m = x;
      for (int k = 32; k >= 1; k >>= 1) m = fmaxf(m, __shfl_xor(m, k));
      float e = (lane < NL) ? expf(x - m) : 0.f;
      float ssum = e;
      for (int k = 32; k >= 1; k >>= 1) ssum += __shfl_xor(ssum, k);
      if (lane < NL) wgt[NV + lane] = e / ssum;
    }
    __syncthreads();
    const __hip_bfloat16* vb = vvb + (long)b * NV * 1024 + tid;
    float a0 = 0.f, a1 = 0.f, a2 = 0.f, a3 = 0.f;
#pragma unroll
    for (int n = 0; n < NV; n += 4) {
      a0 += __bfloat162float(vb[(long)(n + 0) * 1024]) * wgt[n + 0];
      a1 += __bfloat162float(vb[(long)(n + 1) * 1024]) * wgt[n + 1];
      a2 += __bfloat162float(vb[(long)(n + 2) * 1024]) * wgt[n + 2];
      a3 += __bfloat162float(vb[(long)(n + 3) * 1024]) * wgt[n + 3];
    }
    const float vc = (a0 + a1) + (a2 + a3);
    const __hip_bfloat16* lb = lvb + (long)b * NL * 1024 + tid;
    float c0 = 0.f, c1 = 0.f, c2 = 0.f, c3 = 0.f;
#pragma unroll
    for (int n = 0; n < NL; n += 4) {
      c0 += __bfloat162float(lb[(long)(n + 0) * 1024]) * wgt[NV + n + 0];
      c1 += __bfloat162float(lb[(long)(n + 1) * 1024]) * wgt[NV + n + 1];
      c2 += __bfloat162float(lb[(long)(n + 2) * 1024]) * wgt[NV + n + 2];
      c3 += __bfloat162float(lb[(long)(n + 3) * 1024]) * wgt[NV + n + 3];
    }
    const float lc = (c0 + c1) + (c2 + c3);
    const long orow = ((long)step * 128 + b) * 1024 + tid;
    vctxB[orow] = __float2bfloat16(vc);
    lctxB[orow] = __float2bfloat16(lc);
    kv = tanhf(kv + vc + lc);
    __syncthreads();
  }
  out_kvs[(long)b * 1024 + tid] = kv;
}

// ---------------------------------------------------------------------------
// fusedD: batched lang-gates GEMM (blocks 0..511, slots 0-3) ||
//         h_att lbase-part GEMM (blocks 512..639, slots 4-7). Independent.
// ---------------------------------------------------------------------------
__global__ __launch_bounds__(512, 4) void fusedD(GemmArgs ga,
                                                 short* __restrict__ gps) {
  __shared__ __align__(16) union { struct { ldsT As; ldsT Bs; } g; } sm;
  const int bid = blockIdx.x;
  if (bid < 512) {
    gemm_body<128>(ga, 4096, gps, bid & 31, (bid >> 5) & 3, bid >> 7,
                   &sm.g.As, &sm.g.Bs);
  } else {
    const int h = bid - 512;                  // 0..127
    gemm_body<128>(ga, 4096, gps, h & 31, 0, 4 + (h >> 5), &sm.g.As, &sm.g.Bs);
  }
}

// ---------------------------------------------------------------------------
// batched lang LSTM (M=512): gates = 4 gpB slots[row] + 8 gpLB slots[b]
// (all bf16) + lbih + lbhh; c_prev = sc1[b].
// ---------------------------------------------------------------------------
__global__ __launch_bounds__(256) void lstm_batch(
    const short* __restrict__ gps, const float* __restrict__ lbih,
    const float* __restrict__ lbhh, const float* __restrict__ sc1,
    float* __restrict__ hB, float* __restrict__ cB) {
  long idx = ((long)blockIdx.x * 256 + threadIdx.x) * 4;
  if (idx >= 512L * 1024) return;
  const int row = (int)(idx >> 10);   // step*128+b
  const int b = row & 127;
  const int d = (int)(idx & 1023);
  const long base = (long)row * 4096 + d;
  const long bbase = (long)b * 4096 + d;
  f32x4 g[4];
#pragma unroll
  for (int gi = 0; gi < 4; ++gi) {
    const long o = gi * 1024;
    f32x4 v = LD4(lbih + gi * 1024 + d) + LD4(lbhh + gi * 1024 + d);
#pragma unroll
    for (int s = 0; s < 4; ++s) v += ld4bf(gps + SGPB + s * SLBs + base + o);
#pragma unroll
    for (int s = 0; s < 8; ++s) v += ld4bf(gps + SGPLB + s * SLs + bbase + o);
    g[gi] = v;
  }
  f32x4 cp = LD4(sc1 + (long)b * 1024 + d), cc, hh;
#pragma unroll
  for (int j = 0; j < 4; ++j) {
    float ccj = sigf(g[1][j]) * cp[j] + sigf(g[0][j]) * tanhf(g[2][j]);
    cc[j] = ccj;
    hh[j] = sigf(g[3][j]) * tanhf(ccj);
  }
  ST4(cB + idx, cc);
  ST4(hB + idx, hh);
}

// ---------------------------------------------------------------------------
// fusedC: conf GEMM (blocks 0..127, slots 0-3) || key-output finalize
// (128..1919): stages S[b][d] = sum_steps hB in LDS, out = key + 0.01*S.
// ---------------------------------------------------------------------------
__global__ __launch_bounds__(512, 4) void fusedC(
    GemmArgs ga, short* __restrict__ gps, const float* __restrict__ hB,
    const __hip_bfloat16* __restrict__ vkb, const __hip_bfloat16* __restrict__ lkb,
    float* __restrict__ out) {
  __shared__ __align__(16) union {
    struct { ldsT As; ldsT Bs; } g;
    struct { float Ssh[1024]; } f;
  } sm;
  const int bid = blockIdx.x;
  if (bid < 128) {
    gemm_body<128>(ga, 1024, gps, bid & 7, (bid >> 3) & 3, bid >> 5,
                   &sm.g.As, &sm.g.Bs);
    return;
  }
  const int fb = bid - 128;                 // 0..1791
  const long base = (long)fb * 4096;
  const bool isV = (base < VK);
  const int b = isV ? (int)(base / (NV * 1024))
                    : (int)((base - VK) / (NL * 1024));
  const int tid = threadIdx.x;
  for (int d = tid; d < 1024; d += 512) {
    float s = 0.f;
#pragma unroll
    for (int st = 0; st < 4; ++st) s += hB[((long)st * 128 + b) * 1024 + d];
    sm.f.Ssh[d] = s;
  }
  __syncthreads();
  const long idx = base + (long)tid * 8;
  const int d = (int)(idx & 1023);
  if (isV) {
    s16x8 k8 = *(const s16x8*)((const short*)vkb + idx);
    f32x4 o0, o1;
#pragma unroll
    for (int j = 0; j < 4; ++j) {
      o0[j] = bf2f(k8[j]) + 0.01f * sm.f.Ssh[d + j];
      o1[j] = bf2f(k8[j + 4]) + 0.01f * sm.f.Ssh[d + 4 + j];
    }
    ST4(out + O1 + idx, o0);
    ST4(out + O1 + idx + 4, o1);
  } else {
    const long r = idx - VK;
    s16x8 k8 = *(const s16x8*)((const short*)lkb + r);
    f32x4 o0, o1;
#pragma unroll
    for (int j = 0; j < 4; ++j) {
      o0[j] = bf2f(k8[j]) + 0.01f * sm.f.Ssh[d + j];
      o1[j] = bf2f(k8[j + 4]) + 0.01f * sm.f.Ssh[d + 4 + j];
    }
    ST4(out + O2 + r, o0);
    ST4(out + O2 + r + 4, o1);
  }
}

// ---------------------------------------------------------------------------
// halt_scan: per-b halting recurrence over 4 steps (sums 4 bf16 conf slots).
// ---------------------------------------------------------------------------
__global__ __launch_bounds__(256) void halt_scan(
    const short* __restrict__ gps, const float* __restrict__ cb1,
    const float* __restrict__ W2, const float* __restrict__ b2,
    const float* __restrict__ hB, const float* __restrict__ cB,
    const int* __restrict__ it, float* __restrict__ out) {
  const int b = blockIdx.x, tid = threadIdx.x;
  const int d0 = tid * 4;
  __shared__ float red[256];
  __shared__ float p_sh;
  const f32x4 w4 = LD4(W2 + d0);
  const f32x4 cb = LD4(cb1 + d0);
  f32x4 hl_acc = (f32x4){0.f, 0.f, 0.f, 0.f}, cl_acc = hl_acc;
  float a = 0.f, sel = 1.f, cost = 0.f;

  for (int i = 0; i < 4; ++i) {
    const long o = ((long)i * 128 + b) * 1024 + d0;
    f32x4 rv = cb;
#pragma unroll
    for (int s = 0; s < 4; ++s) rv += ld4bf(gps + SGPC + s * SLCs + o);
    float part = 0.f;
#pragma unroll
    for (int j = 0; j < 4; ++j) part += fmaxf(rv[j], 0.f) * w4[j];
    red[tid] = part;
    __syncthreads();
    for (int s = 128; s > 0; s >>= 1) {
      if (tid < s) red[tid] += red[tid + s];
      __syncthreads();
    }
    if (tid == 0) p_sh = sigf(red[0] + b2[0]);
    __syncthreads();
    const float p = p_sh;
    const float bs = p * (1.f - a) * sel;
    f32x4 hl = LD4(hB + o), cl = LD4(cB + o);
    hl_acc += hl * bs;
    cl_acc += cl * bs;
    cost += (float)(i + 1) * (1.f - p) * sel;
    a += bs;
    sel = (a < 1.f - EPS) ? sel : 0.f;
    __syncthreads();
  }
  const float inv_a = 1.f / a;
  const long ob = (long)b * 1024 + d0;
  ST4(out + ob, hl_acc * inv_a);             // outA
  ST4(out + O4 + BD + ob, hl_acc * inv_a);   // new_h[1]
  ST4(out + O5 + BD + ob, cl_acc * inv_a);   // new_c[1]
  if (tid == 0) out[O3 + b] = cost * ((it[b] > 0) ? 1.f : 0.f);
}

// ---------------------------------------------------------------------------
extern "C" void kernel_launch(void* const* d_in, const int* in_sizes, int n_in,
                              void* d_out, int out_size, void* d_ws, size_t ws_size,
                              hipStream_t stream) {
  const float* xt   = (const float*)d_in[0];
  const int*   it   = (const int*)d_in[1];
  const float* fc   = (const float*)d_in[2];
  const float* vval = (const float*)d_in[3];
  const float* vkey = (const float*)d_in[4];
  const float* lval = (const float*)d_in[5];
  const float* lkey = (const float*)d_in[6];
  const float* kv0  = (const float*)d_in[7];
  const float* sh   = (const float*)d_in[8];   // [2,B,D]
  const float* sc   = (const float*)d_in[9];   // [2,B,D]
  // d_in[10] = max_att_step (4)
  const float* aWih = (const float*)d_in[11];  // [4096,3072]
  const float* aWhh = (const float*)d_in[12];  // [4096,1024]
  const float* abih = (const float*)d_in[13];
  const float* abhh = (const float*)d_in[14];
  const float* lWih = (const float*)d_in[15];  // [4096,3072]
  const float* lWhh = (const float*)d_in[16];  // [4096,1024]
  const float* lbih = (const float*)d_in[17];
  const float* lbhh = (const float*)d_in[18];
  const float* cW1  = (const float*)d_in[19];  // [1024,1024]
  const float* cb1  = (const float*)d_in[20];
  const float* cW2  = (const float*)d_in[21];  // [1,1024]
  const float* cb2  = (const float*)d_in[22];

  float* ws = (float*)d_ws;
  short* gps = (short*)d_ws;
  float* h_att = ws + OFF_HATT;
  float* hB    = ws + OFF_HLB;
  float* cB    = ws + OFF_CLB;
  __hip_bfloat16* vvb  = (__hip_bfloat16*)(ws + OFF_VVB);
  __hip_bfloat16* lvb  = (__hip_bfloat16*)(ws + OFF_LVB);
  __hip_bfloat16* vkb  = (__hip_bfloat16*)(ws + OFF_VKB);
  __hip_bfloat16* lkb  = (__hip_bfloat16*)(ws + OFF_LKB);
  __hip_bfloat16* hatb = (__hip_bfloat16*)(ws + OFF_HATB);
  __hip_bfloat16* vcxb = (__hip_bfloat16*)(ws + OFF_VCXB);
  __hip_bfloat16* lcxb = (__hip_bfloat16*)(ws + OFF_LCXB);

  const float* sh1 = sh + BD;  // state_h[1]
  const float* sc0 = sc;       // state_c[0]
  const float* sc1 = sc + BD;  // state_c[1]
  float* out = (float*)d_out;

  // 1) fusedA: conv (256 blocks) || BN=64 20-slot GEMM (1280 blocks)
  {
    GemmArgs ga = {};
    const float* Aops[4] = {sh1, fc, xt, sh};
    const float* Wops[4] = {aWih, aWih + 1024, aWih + 2048, aWhh};
    const long wstrs[4] = {3072, 3072, 3072, 1024};
    for (int p = 0; p < 4; ++p)
      for (int q = 0; q < 4; ++q) {
        const int s = p * 4 + q;
        ga.A[s] = Aops[p] + q * 256;
        ga.W[s] = Wops[p] + q * 256;
        ga.wstride[s] = wstrs[p];
        ga.ooff[s] = SGPA + (long)s * SLs;
        ga.klen[s] = 256;
      }
    for (int q = 0; q < 4; ++q) {           // sh1 @ lWhh quarters -> gpLB 0-3
      const int s = 16 + q;
      ga.A[s] = sh1 + q * 256;
      ga.W[s] = lWhh + q * 256;
      ga.wstride[s] = 1024;
      ga.ooff[s] = SGPLB + (long)q * SLs;
      ga.klen[s] = 256;
    }
    fusedA<<<1536, 512, 0, stream>>>(ga, gps, vkey, lkey, vval, lval,
                                     vkb, lkb, vvb, lvb);
  }
  // 2) att LSTM -> h_att f32+bf16 (+ new_h[0]/new_c[0] to out)
  lstm_att<<<128, 256, 0, stream>>>(gps, abih, abhh, sc0, h_att, hatb, out);

  // 3) attention (proven 1024-thread LDS-key form)
  attn_mega<<<128, 1024, 0, stream>>>(h_att, kv0, vkb, lkb, vvb, lvb,
                                      vcxb, lcxb, out + O6);

  // 4) fusedD: batched gates GEMM (slots 0-3) || h_att lbase GEMM (slots 4-7)
  {
    GemmArgs ga = {};
    ga.A[0] = vcxb;                                    ga.W[0] = lWih;
    ga.wstride[0] = 3072; ga.abf16[0] = 1;
    ga.ooff[0] = SGPB;             ga.klen[0] = 512;
    ga.A[1] = (const void*)((const short*)vcxb + 512); ga.W[1] = lWih + 512;
    ga.wstride[1] = 3072; ga.abf16[1] = 1;
    ga.ooff[1] = SGPB + SLBs;      ga.klen[1] = 512;
    ga.A[2] = lcxb;                                    ga.W[2] = lWih + 1024;
    ga.wstride[2] = 3072; ga.abf16[2] = 1;
    ga.ooff[2] = SGPB + 2 * SLBs;  ga.klen[2] = 512;
    ga.A[3] = (const void*)((const short*)lcxb + 512); ga.W[3] = lWih + 1536;
    ga.wstride[3] = 3072; ga.abf16[3] = 1;
    ga.ooff[3] = SGPB + 3 * SLBs;  ga.klen[3] = 512;
    for (int q = 0; q < 4; ++q) {           // hatb @ lWih[:,2048:] quarters
      const int s = 4 + q;
      ga.A[s] = (const void*)((const short*)hatb + q * 256);
      ga.W[s] = lWih + 2048 + q * 256;
      ga.wstride[s] = 3072;
      ga.abf16[s] = 1;
      ga.ooff[s] = SGPLB + (long)(4 + q) * SLs;
      ga.klen[s] = 256;
    }
    fusedD<<<640, 512, 0, stream>>>(ga, gps);
  }
  // 5) batched lang LSTM (4 gpB slots + 8 gpLB slots + biases)
  lstm_batch<<<512, 256, 0, stream>>>(gps, lbih, lbhh, sc1, hB, cB);

  // 6) fusedC: conf GEMM (128) || key-output finalize (1792)
  {
    GemmArgs ga = {};
    for (int q = 0; q < 4; ++q) {
      ga.A[q] = hB + q * 256;
      ga.W[q] = cW1 + q * 256;
      ga.wstride[q] = 1024;
      ga.ooff[q] = SGPC + (long)q * SLCs;
      ga.klen[q] = 256;
    }
    fusedC<<<1920, 512, 0, stream>>>(ga, gps, hB, vkb, lkb, out);
  }
  // 7) halting scan -> outA, new_h[1], new_c[1], cost
  halt_scan<<<128, 256, 0, stream>>>(gps, cb1, cW2, cb2, hB, cB, it, out);
}